// Round 13
// baseline (481.617 us; speedup 1.0000x reference)
//
#include <hip/hip_runtime.h>
#include <cmath>

#define B_   32
#define N_   512
#define E_   8192
#define BN_  16384
#define D_   128

typedef short bf16x8 __attribute__((ext_vector_type(8)));
typedef float f32x4  __attribute__((ext_vector_type(4)));

static __device__ __forceinline__ float bf2f(unsigned short u){
  union{unsigned int i; float f;} v; v.i = ((unsigned int)u)<<16; return v.f;
}
static __device__ __forceinline__ unsigned short f2bf(float f){
  union{unsigned int i; float f;} v; v.f=f;
  unsigned int x=v.i;
  return (unsigned short)((x + 0x7fffu + ((x>>16)&1u))>>16);
}
static __device__ __forceinline__ unsigned int pack2(float a, float b){
  return (unsigned int)f2bf(a) | ((unsigned int)f2bf(b)<<16);
}
// fast GELU: A&S 7.1.26 erf, |err|<=1.5e-7 (below bf16 noise)
static __device__ __forceinline__ float gelu_f(float x){
  float xs=x*0.70710678118654752f;
  float ax=fabsf(xs);
  float t=__builtin_amdgcn_rcpf(1.0f+0.3275911f*ax);
  float p=t*(0.254829592f+t*(-0.284496736f+t*(1.421413741f+t*(-1.453152027f+t*1.061405429f))));
  float er=1.0f - p*__expf(-ax*ax);
  er = (xs<0.f)? -er : er;
  return 0.5f*x*(1.0f+er);
}
static __device__ __forceinline__ float ldin(const void* p, size_t i, int isbf){
  return isbf ? bf2f(((const unsigned short*)p)[i]) : ((const float*)p)[i];
}

static __device__ __forceinline__ void block_sum2(float a, float b, float&A, float&Bv, float* red, int nw){
  int lane=threadIdx.x&63, w=threadIdx.x>>6;
  #pragma unroll
  for(int o=32;o>0;o>>=1){ a+=__shfl_down(a,o); b+=__shfl_down(b,o); }
  if(lane==0){ red[w]=a; red[8+w]=b; }
  __syncthreads();
  float sa=0.f, sb=0.f;
  for(int i=0;i<nw;i++){ sa+=red[i]; sb+=red[8+i]; }
  __syncthreads();
  A=sa; Bv=sb;
}

// ---------------- dtype sniff ----------------
__global__ void sniff_kernel(const unsigned int* __restrict__ xw, int* __restrict__ flag){
  int t=threadIdx.x;
  int cnt=0;
  for(int i=0;i<32;i++){
    unsigned int w=xw[t+64*i];
    float v=bf2f((unsigned short)(w&0xffffu));
    float av=fabsf(v);
    if(v==0.0f || (av>=6e-5f && av<=8.0f)) cnt++;
  }
  #pragma unroll
  for(int o=32;o>0;o>>=1) cnt+=__shfl_down(cnt,o);
  if(t==0) *flag=(cnt>=1024)?1:0;
}

// ---------------- counting sort by dst + CSR rowptr ----------------
__global__ __launch_bounds__(256) void sort_kernel(
  const int* __restrict__ src, const int* __restrict__ dst,
  unsigned short* __restrict__ ss, int* __restrict__ rowptr)
{
  __shared__ int cnt[512];
  __shared__ int off[512];
  int g=blockIdx.x, t=threadIdx.x;
  for(int i=t;i<512;i+=256) cnt[i]=0;
  __syncthreads();
  for(int e=t;e<E_;e+=256) atomicAdd(&cnt[dst[g*E_+e]],1);
  __syncthreads();
  if(t==0){ int acc=0; for(int i=0;i<512;i++){ off[i]=acc; acc+=cnt[i]; } }
  __syncthreads();
  for(int i=t;i<512;i+=256) rowptr[g*513+i]=off[i];
  if(t==0) rowptr[g*513+512]=E_;
  __syncthreads();
  for(int e=t;e<E_;e+=256){
    int d=dst[g*E_+e];
    int pos=atomicAdd(&off[d],1);
    ss[g*E_+pos]=(unsigned short)src[g*E_+e];
  }
}

// cb layout (bf16 canonical):
// [0,1152) qkv bias | [1152,1536) ob | [1536,1920) msg_b1 | [1920,2304) msg_b2
// [2304,2688) msg_g | [2688,3072) msg_bb | [3072,3456) attn_g | [3456,3840) attn_b
// [3840,4096) enc_b1 | [4096,4352) enc_g1 | [4352,4608) enc_bn1
// [4608,4736) enc_b2 | [4736,4864) enc_g2 | [4864,4992) enc_bn2
// [4992,5248) gh_b1 | [5248,5504) gh_g | [5504,5760) gh_bn | [5760,5776) gh_b2
__global__ __launch_bounds__(256) void prep_kernel(
  const void* __restrict__ msg_w1, const void* __restrict__ msg_w2,
  const void* __restrict__ qw, const void* __restrict__ kw,
  const void* __restrict__ vw, const void* __restrict__ ow,
  const void* __restrict__ qb, const void* __restrict__ kb, const void* __restrict__ vb,
  const void* __restrict__ ob, const void* __restrict__ msg_b1, const void* __restrict__ msg_b2,
  const void* __restrict__ msg_g, const void* __restrict__ msg_bb,
  const void* __restrict__ attn_g, const void* __restrict__ attn_b,
  const void* __restrict__ enc_w1, const void* __restrict__ enc_w2,
  const void* __restrict__ enc_b1, const void* __restrict__ enc_g1, const void* __restrict__ enc_bn1,
  const void* __restrict__ enc_b2, const void* __restrict__ enc_g2, const void* __restrict__ enc_bn2,
  const void* __restrict__ gh_w1, const void* __restrict__ gh_w2,
  const void* __restrict__ gh_b1, const void* __restrict__ gh_g,
  const void* __restrict__ gh_bn, const void* __restrict__ gh_b2,
  unsigned short* __restrict__ w1t, unsigned short* __restrict__ w2k,
  unsigned short* __restrict__ qkvt, unsigned short* __restrict__ owt,
  unsigned short* __restrict__ w1te, unsigned short* __restrict__ w2te,
  unsigned short* __restrict__ ghw1t, unsigned short* __restrict__ ghw2t,
  unsigned short* __restrict__ cb, const int* __restrict__ flag)
{
  int isbf=*flag;
  int job=blockIdx.y;
  int i=blockIdx.x*256+threadIdx.x;
  if(job<3){ // msg_w1[l] [256][128] -> [128][256] n-major
    if(i<32768){ int l=job; int k=i>>7, n=i&127; w1t[l*32768 + n*256 + k]=f2bf(ldin(msg_w1,(size_t)l*32768+i,isbf)); }
  } else if(job<6){ // msg_w2[l] straight copy [128k][128n]
    int l=job-3; if(i<16384){ w2k[l*16384 + i]=f2bf(ldin(msg_w2,(size_t)l*16384+i,isbf)); }
  } else if(job<15){
    int r=job-6, l=r/3, which=r%3;
    if(i<16384){ int k=i>>7, n=i&127;
      const void* w=(which==0)?qw:((which==1)?kw:vw);
      qkvt[l*49152 + (which*128+n)*128 + k]=f2bf(ldin(w,(size_t)l*16384+i,isbf)); }
  } else if(job<18){
    int l=job-15; if(i<16384){ int k=i>>7, n=i&127; owt[l*16384 + n*128 + k]=f2bf(ldin(ow,(size_t)l*16384+i,isbf)); }
  } else if(job==18){
    if(i<3840){
      float v;
      if(i<1152){ int l=i/384, j=i%384, which=j>>7, jj=j&127;
        const void* bb=(which==0)?qb:((which==1)?kb:vb);
        v=ldin(bb,(size_t)l*128+jj,isbf);
      } else {
        int i2=i-1152; int r=i2/384; int rem=i2%384;
        const void* s = (r==0)?ob:((r==1)?msg_b1:((r==2)?msg_b2:((r==3)?msg_g:((r==4)?msg_bb:((r==5)?attn_g:attn_b)))));
        v=ldin(s,(size_t)rem,isbf);
      }
      cb[i]=f2bf(v);
    }
  } else if(job==19){
    if(i<1152){
      float v;
      if(i<256)       v=ldin(enc_b1,i,isbf);
      else if(i<512)  v=ldin(enc_g1,i-256,isbf);
      else if(i<768)  v=ldin(enc_bn1,i-512,isbf);
      else if(i<896)  v=ldin(enc_b2,i-768,isbf);
      else if(i<1024) v=ldin(enc_g2,i-896,isbf);
      else            v=ldin(enc_bn2,i-1024,isbf);
      cb[3840+i]=f2bf(v);
    }
  } else if(job==20){
    if(i<16384){ int k=i>>8, n=i&255; w1te[n*64+k]=f2bf(ldin(enc_w1,(size_t)i,isbf)); }
  } else if(job==21){
    if(i<32768){ int k=i>>7, n=i&127; w2te[n*256+k]=f2bf(ldin(enc_w2,(size_t)i,isbf)); }
  } else if(job<26){
    int p=job-22; int j=p*32768+i;
    if(i<32768){ int k=j>>8, n=j&255; ghw1t[n*512+k]=f2bf(ldin(gh_w1,(size_t)j,isbf)); }
  } else {
    if(i<2560){ int k=i/10, n=i%10; ghw2t[n*256+k]=f2bf(ldin(gh_w2,(size_t)i,isbf)); }
    else if(i<2560+778){
      int j=i-2560; float v;
      if(j<256)      v=ldin(gh_b1,j,isbf);
      else if(j<512) v=ldin(gh_g,j-256,isbf);
      else if(j<768) v=ldin(gh_bn,j-512,isbf);
      else           v=ldin(gh_b2,j-768,isbf);
      cb[4992+j]=f2bf(v);
    }
  }
}

// ---------------- fused node encoder ----------------
__global__ __launch_bounds__(256) void enc_kernel(
  const void* __restrict__ x, const unsigned short* __restrict__ w1te,
  const unsigned short* __restrict__ w2te, const unsigned short* __restrict__ cb,
  unsigned short* __restrict__ h, const int* __restrict__ flag)
{
  __shared__ __align__(16) unsigned short xs[64][72];
  __shared__ __align__(16) unsigned short t1[64][264];
  int isbf=*flag;
  int m0=blockIdx.x*64;
  int t=threadIdx.x, lane=t&63, w=t>>6, quad=lane>>4, ln=lane&15;
  for(int c2=t;c2<1024;c2+=256){
    int i=c2*4, row=i>>6, col=i&63;
    float v0,v1,v2,v3;
    if(isbf){
      const unsigned short* p=(const unsigned short*)x+(size_t)m0*64+i;
      v0=bf2f(p[0]); v1=bf2f(p[1]); v2=bf2f(p[2]); v3=bf2f(p[3]);
    } else {
      float4 f=*(const float4*)((const float*)x+(size_t)m0*64+i);
      v0=f.x; v1=f.y; v2=f.z; v3=f.w;
    }
    ushort4 o; o.x=f2bf(v0); o.y=f2bf(v1); o.z=f2bf(v2); o.w=f2bf(v3);
    *(ushort4*)&xs[row][col]=o;
  }
  __syncthreads();
  f32x4 a[4][4];
  #pragma unroll
  for(int nt=0;nt<4;nt++){ a[nt][0]={0,0,0,0}; a[nt][1]={0,0,0,0}; a[nt][2]={0,0,0,0}; a[nt][3]={0,0,0,0}; }
  #pragma unroll
  for(int k0i=0;k0i<2;k0i++){
    bf16x8 af[4];
    #pragma unroll
    for(int f=0;f<4;f++) af[f]=*(const bf16x8*)(&xs[f*16+ln][k0i*32+quad*8]);
    #pragma unroll
    for(int nt=0;nt<4;nt++){
      int n=w*64+nt*16+ln;
      bf16x8 bfr=*(const bf16x8*)(w1te+(size_t)n*64+k0i*32+quad*8);
      #pragma unroll
      for(int f=0;f<4;f++) a[nt][f]=__builtin_amdgcn_mfma_f32_16x16x32_bf16(af[f],bfr,a[nt][f],0,0,0);
    }
  }
  #pragma unroll
  for(int nt=0;nt<4;nt++){
    int n=w*64+nt*16+ln;
    float bv=bf2f(cb[3840+n]);
    #pragma unroll
    for(int f=0;f<4;f++)
      #pragma unroll
      for(int r=0;r<4;r++) t1[f*16+quad*4+r][n]=f2bf(a[nt][f][r]+bv);
  }
  __syncthreads();
  {
    int row=t>>2, qq=t&3;
    float s=0.f,s2=0.f;
    for(int c=qq*64;c<qq*64+64;c++){ float v=bf2f(t1[row][c]); s+=v; s2+=v*v; }
    s+=__shfl_xor(s,1); s+=__shfl_xor(s,2);
    s2+=__shfl_xor(s2,1); s2+=__shfl_xor(s2,2);
    float mu=s*(1.f/256.f), var=fmaxf(s2*(1.f/256.f)-mu*mu,0.f);
    float rr=rsqrtf(var+1e-5f);
    for(int c=qq*64;c<qq*64+64;c++){
      float v=bf2f(t1[row][c]);
      t1[row][c]=f2bf(gelu_f((v-mu)*rr*bf2f(cb[4096+c])+bf2f(cb[4352+c])));
    }
  }
  __syncthreads();
  f32x4 b2a[2][4];
  #pragma unroll
  for(int nt=0;nt<2;nt++){ b2a[nt][0]={0,0,0,0}; b2a[nt][1]={0,0,0,0}; b2a[nt][2]={0,0,0,0}; b2a[nt][3]={0,0,0,0}; }
  #pragma unroll
  for(int k0i=0;k0i<8;k0i++){
    bf16x8 af[4];
    #pragma unroll
    for(int f=0;f<4;f++) af[f]=*(const bf16x8*)(&t1[f*16+ln][k0i*32+quad*8]);
    #pragma unroll
    for(int nt=0;nt<2;nt++){
      int n=w*32+nt*16+ln;
      bf16x8 bfr=*(const bf16x8*)(w2te+(size_t)n*256+k0i*32+quad*8);
      #pragma unroll
      for(int f=0;f<4;f++) b2a[nt][f]=__builtin_amdgcn_mfma_f32_16x16x32_bf16(af[f],bfr,b2a[nt][f],0,0,0);
    }
  }
  __syncthreads();
  float* mf=(float*)&t1[0][0];   // [64][132]
  #pragma unroll
  for(int nt=0;nt<2;nt++){
    int n=w*32+nt*16+ln;
    float bv=bf2f(cb[4608+n]);
    #pragma unroll
    for(int f=0;f<4;f++)
      #pragma unroll
      for(int r=0;r<4;r++) mf[(f*16+quad*4+r)*132+n]=b2a[nt][f][r]+bv;
  }
  __syncthreads();
  {
    int row=t>>2, qq=t&3;
    float s=0.f,s2=0.f;
    for(int c=qq*32;c<qq*32+32;c++){ float v=mf[row*132+c]; s+=v; s2+=v*v; }
    s+=__shfl_xor(s,1); s+=__shfl_xor(s,2);
    s2+=__shfl_xor(s2,1); s2+=__shfl_xor(s2,2);
    float mu=s*(1.f/128.f), var=fmaxf(s2*(1.f/128.f)-mu*mu,0.f);
    float rr=rsqrtf(var+1e-5f);
    for(int c=qq*32;c<qq*32+32;c+=2){
      float v0=(mf[row*132+c  ]-mu)*rr*bf2f(cb[4736+c  ])+bf2f(cb[4864+c  ]);
      float v1=(mf[row*132+c+1]-mu)*rr*bf2f(cb[4736+c+1])+bf2f(cb[4864+c+1]);
      *(unsigned int*)(h+(size_t)(m0+row)*128+c)=pack2(v0,v1);
    }
  }
}

// ---------------- UV generation: U = h@W1a + b1, V = h@W1b ----------------
__global__ __launch_bounds__(256) void uvgen_kernel(
  const unsigned short* __restrict__ hrows, const unsigned short* __restrict__ w1t,
  const unsigned short* __restrict__ b1, unsigned short* __restrict__ UV)
{
  __shared__ __align__(16) unsigned short a_t[64][136];
  int t=threadIdx.x;
  int m0=blockIdx.x*64;
  int y=blockIdx.y;
  for(int c=t;c<1024;c+=256){
    int m=c>>4, pp=c&15;
    *(uint4*)&a_t[m][pp*8]=*((const uint4*)(hrows+(size_t)(m0+m)*128)+pp);
  }
  __syncthreads();
  int lane=t&63, w=t>>6, quad=lane>>4, ln=lane&15;
  #pragma unroll
  for(int nt=0;nt<2;nt++){
    int n=w*32+nt*16+ln;
    f32x4 a0={0,0,0,0},a1={0,0,0,0},a2={0,0,0,0},a3={0,0,0,0};
    const unsigned short* wp=w1t+(size_t)n*256+y*128+quad*8;
    #pragma unroll
    for(int k0=0;k0<128;k0+=32){
      bf16x8 bfr=*(const bf16x8*)(wp+k0);
      bf16x8 f0=*(const bf16x8*)(&a_t[ln   ][k0+quad*8]);
      bf16x8 f1=*(const bf16x8*)(&a_t[16+ln][k0+quad*8]);
      bf16x8 f2=*(const bf16x8*)(&a_t[32+ln][k0+quad*8]);
      bf16x8 f3=*(const bf16x8*)(&a_t[48+ln][k0+quad*8]);
      a0=__builtin_amdgcn_mfma_f32_16x16x32_bf16(f0,bfr,a0,0,0,0);
      a1=__builtin_amdgcn_mfma_f32_16x16x32_bf16(f1,bfr,a1,0,0,0);
      a2=__builtin_amdgcn_mfma_f32_16x16x32_bf16(f2,bfr,a2,0,0,0);
      a3=__builtin_amdgcn_mfma_f32_16x16x32_bf16(f3,bfr,a3,0,0,0);
    }
    float bv=y?0.f:bf2f(b1[n]);
    #pragma unroll
    for(int r2=0;r2<4;r2++){
      UV[(size_t)(m0+quad*4+r2   )*256+y*128+n]=f2bf(a0[r2]+bv);
      UV[(size_t)(m0+16+quad*4+r2)*256+y*128+n]=f2bf(a1[r2]+bv);
      UV[(size_t)(m0+32+quad*4+r2)*256+y*128+n]=f2bf(a2[r2]+bv);
      UV[(size_t)(m0+48+quad*4+r2)*256+y*128+n]=f2bf(a3[r2]+bv);
    }
  }
}

// ---------------- fused edge phase: 2 waves split edges of 4 dst; XCD-local swizzle ----------------
// blockDim=128. Wave w gathers half of each dst's edges into aggL[w]; after one barrier,
// wave w runs GEMV+LN for dst pair {2w,2w+1}. lg=bid%gEp keeps a graph's blocks on one XCD.
__global__ __launch_bounds__(128) void edgef_kernel(
  unsigned short* __restrict__ h,
  const unsigned short* __restrict__ UV,      // local rows [gEp*512][256]
  const unsigned short* __restrict__ ss,
  const int* __restrict__ rowptr,
  const unsigned short* __restrict__ w2k,     // [128k][128n]
  const unsigned short* __restrict__ b2,
  const unsigned short* __restrict__ gg, const unsigned short* __restrict__ bbp,
  int b0, int gEp)
{
  __shared__ __align__(16) float aggL[2][4][128];
  int t=threadIdx.x, lane=t&63, w=t>>6;
  int bid=blockIdx.x;
  int lg=bid%gEp, ch=bid/gEp;     // ch in [0,128): 4-dst chunk
  int g=b0+lg;
  const unsigned short* UVg = UV + (size_t)lg*512*256;
  const unsigned short* ssg = ss + (size_t)g*E_;
  int dbase = ch*4;
  int bnd[5];
  #pragma unroll
  for(int i=0;i<5;i++) bnd[i]=rowptr[g*513+dbase+i];
  // ---- gather: wave w takes its half of each dst's edge range ----
  #pragma unroll 1
  for(int dd=0;dd<4;dd++){
    int e_lo=bnd[dd], e_hi0=bnd[dd+1];
    int half=(e_hi0-e_lo+1)>>1;
    int es = w ? (e_lo+half) : e_lo;
    int ee = w ? e_hi0       : (e_lo+half);
    unsigned int vdw=*(const unsigned int*)(UVg + (size_t)(dbase+dd)*256 + 128 + lane*2);
    float v0=bf2f((unsigned short)(vdw&0xffffu)), v1=bf2f((unsigned short)(vdw>>16));
    float a0=0.f, a1=0.f;
    // depth-3 pipeline over this wave's range
    int si3,si4,si5;
    unsigned int u0,u1,u2;
    {
      int s0=(es  <ee)? (int)ssg[es  ] : 0;
      int s1=(es+1<ee)? (int)ssg[es+1] : 0;
      int s2=(es+2<ee)? (int)ssg[es+2] : 0;
      si3=(es+3<ee)? (int)ssg[es+3] : 0;
      si4=(es+4<ee)? (int)ssg[es+4] : 0;
      si5=(es+5<ee)? (int)ssg[es+5] : 0;
      s0=__builtin_amdgcn_readfirstlane(s0);
      s1=__builtin_amdgcn_readfirstlane(s1);
      s2=__builtin_amdgcn_readfirstlane(s2);
      u0=*(const unsigned int*)(UVg + (size_t)s0*256 + lane*2);
      u1=*(const unsigned int*)(UVg + (size_t)s1*256 + lane*2);
      u2=*(const unsigned int*)(UVg + (size_t)s2*256 + lane*2);
    }
    #pragma unroll 1
    for(int e=es;e<ee;e++){
      float z0=bf2f((unsigned short)(u0&0xffffu))+v0;
      float z1=bf2f((unsigned short)(u0>>16))+v1;
      u0=u1; u1=u2;
      int s3=__builtin_amdgcn_readfirstlane(si3);
      u2=*(const unsigned int*)(UVg + (size_t)s3*256 + lane*2);
      si3=si4; si4=si5;
      int en=e+6;
      si5=(en<ee)? (int)ssg[en] : 0;
      a0+=gelu_f(z0); a1+=gelu_f(z1);
    }
    aggL[w][dd][lane*2  ]=a0;
    aggL[w][dd][lane*2+1]=a1;
  }
  __syncthreads();
  // ---- GEMV + residual + LN: wave w owns dst pair {2w, 2w+1} ----
  float o[2][2];
  #pragma unroll
  for(int p=0;p<2;p++){
    int di=w*2+p;
    float deg=(float)(bnd[di+1]-bnd[di]);
    o[p][0]=bf2f(b2[lane*2  ])*deg;
    o[p][1]=bf2f(b2[lane*2+1])*deg;
  }
  #pragma unroll 4
  for(int k=0;k<128;k++){
    unsigned int wdw=*(const unsigned int*)(w2k+(size_t)k*128+lane*2);
    float w0=bf2f((unsigned short)(wdw&0xffffu));
    float w1=bf2f((unsigned short)(wdw>>16));
    #pragma unroll
    for(int p=0;p<2;p++){
      float av=aggL[0][w*2+p][k]+aggL[1][w*2+p][k];
      o[p][0]+=av*w0; o[p][1]+=av*w1;
    }
  }
  #pragma unroll 1
  for(int p=0;p<2;p++){
    int d = dbase + w*2 + p;
    size_t base=(size_t)(g*512+d)*128;
    unsigned int hdw=*(const unsigned int*)(h+base+lane*2);
    float x0=bf2f((unsigned short)(hdw&0xffffu))+o[p][0];
    float x1=bf2f((unsigned short)(hdw>>16))+o[p][1];
    float s1=x0+x1, s2=x0*x0+x1*x1;
    #pragma unroll
    for(int off=32;off>0;off>>=1){ s1+=__shfl_xor(s1,off); s2+=__shfl_xor(s2,off); }
    float mu=s1*(1.f/128.f), var=fmaxf(s2*(1.f/128.f)-mu*mu,0.f);
    float rr=rsqrtf(var+1e-5f);
    float y0=(x0-mu)*rr*bf2f(gg[lane*2  ])+bf2f(bbp[lane*2  ]);
    float y1=(x1-mu)*rr*bf2f(gg[lane*2+1])+bf2f(bbp[lane*2+1]);
    *(unsigned int*)(h+base+lane*2)=pack2(y0,y1);
  }
}

// ---------------- fused QKV + flash attention: per (graph, head, q-QUARTER), XCD-local swizzle ----------------
__global__ __launch_bounds__(256) void attnf_kernel(
  const unsigned short* __restrict__ h, const unsigned short* __restrict__ wqkv,
  const unsigned short* __restrict__ bq, unsigned short* __restrict__ obuf, int b0, int gA)
{
  __shared__ __align__(16) unsigned short Qs[128][40];
  __shared__ __align__(16) unsigned short Ks[64][72];
  __shared__ __align__(16) unsigned short Vts[32][72];
  __shared__ __align__(16) unsigned short Ps[64][72];
  int bx=blockIdx.x;
  int lg=bx%gA; int rr2=bx/gA; int hh=rr2&3, qq4=rr2>>2;
  int g=b0+lg;
  int t=threadIdx.x, lane=t&63, w=t>>6, quad=lane>>4, ln=lane&15;
  const unsigned short* hg=h+(size_t)g*512*128;
  const float sc=0.17677669529663689f;
  bf16x8 wk[2][4], wv[2][4];
  #pragma unroll
  for(int nt=0;nt<2;nt++)
    #pragma unroll
    for(int k0i=0;k0i<4;k0i++){
      int n=hh*32+nt*16+ln;
      wk[nt][k0i]=*(const bf16x8*)(wqkv+(size_t)(128+n)*128+k0i*32+quad*8);
      wv[nt][k0i]=*(const bf16x8*)(wqkv+(size_t)(256+n)*128+k0i*32+quad*8);
    }
  #pragma unroll
  for(int qt=0;qt<2;qt++){
    int r0=qq4*128+qt*64+w*16;
    bf16x8 af[4];
    #pragma unroll
    for(int k0i=0;k0i<4;k0i++) af[k0i]=*(const bf16x8*)(hg+(size_t)(r0+ln)*128+k0i*32+quad*8);
    #pragma unroll
    for(int nt=0;nt<2;nt++){
      int dim=nt*16+ln;
      f32x4 c={0,0,0,0};
      #pragma unroll
      for(int k0i=0;k0i<4;k0i++){
        bf16x8 bfr=*(const bf16x8*)(wqkv+(size_t)(hh*32+dim)*128+k0i*32+quad*8);
        c=__builtin_amdgcn_mfma_f32_16x16x32_bf16(af[k0i],bfr,c,0,0,0);
      }
      float bv=bf2f(bq[hh*32+dim]);
      #pragma unroll
      for(int r=0;r<4;r++) Qs[qt*64+w*16+quad*4+r][dim]=f2bf((c[r]+bv)*sc);
    }
  }
  f32x4 O[2][2]; float Lp[2][4];
  #pragma unroll
  for(int qt=0;qt<2;qt++){ O[qt][0]={0,0,0,0}; O[qt][1]={0,0,0,0};
    #pragma unroll
    for(int r=0;r<4;r++) Lp[qt][r]=0.f; }
  for(int kc=0;kc<8;kc++){
    __syncthreads();
    {
      int r0=kc*64+w*16;
      bf16x8 af[4];
      #pragma unroll
      for(int k0i=0;k0i<4;k0i++) af[k0i]=*(const bf16x8*)(hg+(size_t)(r0+ln)*128+k0i*32+quad*8);
      #pragma unroll
      for(int nt=0;nt<2;nt++){
        int dim=nt*16+ln;
        f32x4 ck={0,0,0,0}, cv={0,0,0,0};
        #pragma unroll
        for(int k0i=0;k0i<4;k0i++){
          ck=__builtin_amdgcn_mfma_f32_16x16x32_bf16(af[k0i],wk[nt][k0i],ck,0,0,0);
          cv=__builtin_amdgcn_mfma_f32_16x16x32_bf16(af[k0i],wv[nt][k0i],cv,0,0,0);
        }
        float bk=bf2f(bq[128+hh*32+dim]), bv2=bf2f(bq[256+hh*32+dim]);
        #pragma unroll
        for(int r=0;r<4;r++){
          int key=w*16+quad*4+r;
          Ks[key][dim]=f2bf(ck[r]+bk);
          Vts[dim][key]=f2bf(cv[r]+bv2);
        }
      }
    }
    __syncthreads();
    #pragma unroll
    for(int qt=0;qt<2;qt++){
      bf16x8 qf=*(const bf16x8*)(&Qs[qt*64+w*16+ln][quad*8]);
      f32x4 s[4];
      #pragma unroll
      for(int f=0;f<4;f++){
        bf16x8 kf=*(const bf16x8*)(&Ks[f*16+ln][quad*8]);
        f32x4 z={0,0,0,0};
        s[f]=__builtin_amdgcn_mfma_f32_16x16x32_bf16(qf,kf,z,0,0,0);
      }
      #pragma unroll
      for(int f=0;f<4;f++)
        #pragma unroll
        for(int r=0;r<4;r++){
          float pe=__expf(fminf(s[f][r],30.0f));
          Ps[w*16+quad*4+r][f*16+ln]=f2bf(pe);
          Lp[qt][r]+=pe;
        }
      #pragma unroll
      for(int s2=0;s2<2;s2++){
        bf16x8 pf=*(const bf16x8*)(&Ps[w*16+ln][s2*32+quad*8]);
        bf16x8 v0=*(const bf16x8*)(&Vts[ln   ][s2*32+quad*8]);
        bf16x8 v1=*(const bf16x8*)(&Vts[16+ln][s2*32+quad*8]);
        O[qt][0]=__builtin_amdgcn_mfma_f32_16x16x32_bf16(pf,v0,O[qt][0],0,0,0);
        O[qt][1]=__builtin_amdgcn_mfma_f32_16x16x32_bf16(pf,v1,O[qt][1],0,0,0);
      }
    }
  }
  #pragma unroll
  for(int qt=0;qt<2;qt++){
    #pragma unroll
    for(int o=1;o<16;o<<=1)
      #pragma unroll
      for(int r=0;r<4;r++) Lp[qt][r]+=__shfl_xor(Lp[qt][r],o);
    #pragma unroll
    for(int r=0;r<4;r++){
      float inv=1.0f/Lp[qt][r];
      size_t row=(size_t)lg*512+qq4*128+qt*64+w*16+quad*4+r;
      obuf[row*128+hh*32+ln   ]=f2bf(O[qt][0][r]*inv);
      obuf[row*128+hh*32+16+ln]=f2bf(O[qt][1][r]*inv);
    }
  }
}

// ---------------- oproj + residual + LN ----------------
__global__ __launch_bounds__(256) void oproj_kernel(
  const unsigned short* __restrict__ obuf, const unsigned short* __restrict__ wo,
  const unsigned short* __restrict__ bo, unsigned short* __restrict__ h,
  const unsigned short* __restrict__ gg, const unsigned short* __restrict__ bbp, int b0)
{
  __shared__ __align__(16) unsigned short a_t[64][136];
  __shared__ float mf[64][132];
  int t=threadIdx.x, lane=t&63, w=t>>6, quad=lane>>4, ln=lane&15;
  int m0=blockIdx.x*64;
  for(int c=t;c<64*16;c+=256){
    int m=c>>4, pp=c&15;
    *(uint4*)&a_t[m][pp*8]=*((const uint4*)(obuf+(size_t)(m0+m)*128)+pp);
  }
  __syncthreads();
  #pragma unroll
  for(int nt=0;nt<2;nt++){
    int n=w*32+nt*16+ln;
    f32x4 a0={0,0,0,0},a1={0,0,0,0},a2={0,0,0,0},a3={0,0,0,0};
    const unsigned short* wp=wo+(size_t)n*128+quad*8;
    #pragma unroll
    for(int k0=0;k0<128;k0+=32){
      bf16x8 bfr=*(const bf16x8*)(wp+k0);
      bf16x8 f0=*(const bf16x8*)(&a_t[ln   ][k0+quad*8]);
      bf16x8 f1=*(const bf16x8*)(&a_t[16+ln][k0+quad*8]);
      bf16x8 f2=*(const bf16x8*)(&a_t[32+ln][k0+quad*8]);
      bf16x8 f3=*(const bf16x8*)(&a_t[48+ln][k0+quad*8]);
      a0=__builtin_amdgcn_mfma_f32_16x16x32_bf16(f0,bfr,a0,0,0,0);
      a1=__builtin_amdgcn_mfma_f32_16x16x32_bf16(f1,bfr,a1,0,0,0);
      a2=__builtin_amdgcn_mfma_f32_16x16x32_bf16(f2,bfr,a2,0,0,0);
      a3=__builtin_amdgcn_mfma_f32_16x16x32_bf16(f3,bfr,a3,0,0,0);
    }
    float bv=bf2f(bo[n]);
    #pragma unroll
    for(int r=0;r<4;r++){
      mf[quad*4+r   ][n]=a0[r]+bv;
      mf[16+quad*4+r][n]=a1[r]+bv;
      mf[32+quad*4+r][n]=a2[r]+bv;
      mf[48+quad*4+r][n]=a3[r]+bv;
    }
  }
  __syncthreads();
  {
    int row=t>>2, qq=t&3;
    size_t base=(size_t)(b0*512+m0+row)*128;
    float s=0.f,s2=0.f;
    float vals[32];
    for(int j=0;j<32;j++){
      int c=qq*32+j;
      float v=bf2f(h[base+c])+mf[row][c];
      vals[j]=v; s+=v; s2+=v*v;
    }
    s+=__shfl_xor(s,1); s+=__shfl_xor(s,2);
    s2+=__shfl_xor(s2,1); s2+=__shfl_xor(s2,2);
    float mu=s*(1.f/128.f), var=fmaxf(s2*(1.f/128.f)-mu*mu,0.f);
    float rr=rsqrtf(var+1e-5f);
    for(int j=0;j<32;j+=2){
      int c=qq*32+j;
      float v0=(vals[j]  -mu)*rr*bf2f(gg[c  ])+bf2f(bbp[c  ]);
      float v1=(vals[j+1]-mu)*rr*bf2f(gg[c+1])+bf2f(bbp[c+1]);
      *(unsigned int*)(h+base+c)=pack2(v0,v1);
    }
  }
}

// ---------------- pooling partials ----------------
__global__ __launch_bounds__(256) void poolp_kernel(
  const unsigned short* __restrict__ h, float* __restrict__ part)
{
  __shared__ float ps[256], ps2[256], pm[256];
  int b=blockIdx.x, c=blockIdx.y;
  int t=threadIdx.x, d=t&127, hf=t>>7;
  float s=0.f,s2=0.f,mx=-1e30f;
  for(int r=hf*32;r<hf*32+32;r++){
    float v=bf2f(h[((size_t)(b*512+c*64+r))*128+d]);
    s+=v; s2+=v*v; mx=fmaxf(mx,v);
  }
  ps[t]=s; ps2[t]=s2; pm[t]=mx;
  __syncthreads();
  if(t<128){
    s=ps[t]+ps[128+t]; s2=ps2[t]+ps2[128+t]; mx=fmaxf(pm[t],pm[128+t]);
    size_t base=((size_t)(b*8+c))*384;
    part[base+t]=s; part[base+128+t]=s2; part[base+256+t]=mx;
  }
}

// ---------------- graph head: finalize pooling + MLP ----------------
__global__ __launch_bounds__(256) void head_kernel(
  const float* __restrict__ part, const unsigned short* __restrict__ ghw1t,
  const unsigned short* __restrict__ ghw2t, const unsigned short* __restrict__ cb,
  void* __restrict__ out, const int* __restrict__ flag)
{
  int isbf=*flag;
  int b=blockIdx.x, t=threadIdx.x;
  __shared__ float pl[512];
  __shared__ float gl[256];
  __shared__ float red[16];
  if(t<128){
    float s=0.f,s2=0.f,mx=-1e30f;
    for(int c=0;c<8;c++){
      size_t base=((size_t)(b*8+c))*384;
      s += part[base+t];
      s2+= part[base+128+t];
      mx = fmaxf(mx, part[base+256+t]);
    }
    float mean=s*(1.f/512.f);
    float var=fmaxf(s2*(1.f/512.f)-mean*mean,0.f);
    float sd=sqrtf(var+1e-6f);
    pl[t]=mean; pl[128+t]=s; pl[256+t]=mx; pl[384+t]=sd;
  }
  __syncthreads();
  float a=bf2f(cb[4992+t]);
  const unsigned short* wr=ghw1t+(size_t)t*512;
  for(int k0=0;k0<512;k0+=8){
    bf16x8 wv=*(const bf16x8*)(wr+k0);
    const unsigned short* wp=(const unsigned short*)&wv;
    #pragma unroll
    for(int j=0;j<8;j++) a+=pl[k0+j]*bf2f(wp[j]);
  }
  float u=gelu_f(a);
  float S,S2; block_sum2(u,u*u,S,S2,red,4);
  float mu=S*(1.f/256.f), var=fmaxf(S2*(1.f/256.f)-mu*mu,0.f);
  float r=rsqrtf(var+1e-5f);
  gl[t]=(u-mu)*r*bf2f(cb[5248+t])+bf2f(cb[5504+t]);
  __syncthreads();
  if(t<10){
    float o=bf2f(cb[5760+t]);
    const unsigned short* wr2=ghw2t+(size_t)t*256;
    for(int k0=0;k0<256;k0+=8){
      bf16x8 wv=*(const bf16x8*)(wr2+k0);
      const unsigned short* wp=(const unsigned short*)&wv;
      #pragma unroll
      for(int j=0;j<8;j++) o+=gl[k0+j]*bf2f(wp[j]);
    }
    if(isbf) ((unsigned short*)out)[b*10+t]=f2bf(o);
    else     ((float*)out)[b*10+t]=o;
  }
}

extern "C" void kernel_launch(void* const* d_in, const int* in_sizes, int n_in,
                              void* d_out, int out_size, void* d_ws, size_t ws_size,
                              hipStream_t stream)
{
  const void* x      =d_in[0];
  const int*  src    =(const int*)d_in[1];
  const int*  dstp   =(const int*)d_in[2];
  const void* enc_w1 =d_in[3];  const void* enc_b1 =d_in[4];
  const void* enc_g1 =d_in[5];  const void* enc_bn1=d_in[6];
  const void* enc_w2 =d_in[7];  const void* enc_b2 =d_in[8];
  const void* enc_g2 =d_in[9];  const void* enc_bn2=d_in[10];
  const void* msg_w1 =d_in[11]; const void* msg_b1 =d_in[12];
  const void* msg_w2 =d_in[13]; const void* msg_b2 =d_in[14];
  const void* msg_g  =d_in[15]; const void* msg_bb =d_in[16];
  const void* qw     =d_in[17]; const void* qb     =d_in[18];
  const void* kw     =d_in[19]; const void* kb     =d_in[20];
  const void* vw     =d_in[21]; const void* vb     =d_in[22];
  const void* ow     =d_in[23]; const void* ob     =d_in[24];
  const void* attn_g =d_in[25]; const void* attn_b =d_in[26];
  const void* gh_w1  =d_in[27]; const void* gh_b1  =d_in[28];
  const void* gh_g   =d_in[29]; const void* gh_bn  =d_in[30];
  const void* gh_w2  =d_in[31]; const void* gh_b2  =d_in[32];
  (void)in_sizes; (void)n_in; (void)out_size;

  const size_t MB=1024*1024;
  char* base=(char*)d_ws;
  unsigned short* h    =(unsigned short*)(base);                 // 4 MB
  unsigned short* w1t  =(unsigned short*)(base + 4194304);
  unsigned short* w2k  =(unsigned short*)(base + 4390912);
  unsigned short* qkvt =(unsigned short*)(base + 4489216);
  unsigned short* owt  =(unsigned short*)(base + 4784128);
  unsigned short* w1te =(unsigned short*)(base + 4882432);
  unsigned short* w2te =(unsigned short*)(base + 4915200);
  unsigned short* ghw1t=(unsigned short*)(base + 4980736);
  unsigned short* ghw2t=(unsigned short*)(base + 5242880);
  unsigned short* cb   =(unsigned short*)(base + 5248000);
  int*   rowptr        =(int*)(base + 5325312);
  int*   flag          =(int*)(base + 5390976);
  unsigned short* ssrt =(unsigned short*)(base + 5505024);       // 512 KB
  char* R              = base + 6029312;                          // shared region

  int epass, apass;
  if(ws_size >= (size_t)(14.5*MB)){ epass=1; apass=1; }
  else if(ws_size >= 10*MB){ epass=2; apass=1; }
  else { epass=4; apass=2; }
  int gEp=B_/epass, gA=B_/apass;
  int rowsA=gA*512;
  float* part=(float*)R;   // pool partials: 32*8*384*4 = 393 KB (R free after layer loop)

  sniff_kernel<<<1,64,0,stream>>>((const unsigned int*)x, flag);
  sort_kernel<<<B_,256,0,stream>>>(src,dstp,ssrt,rowptr);
  prep_kernel<<<dim3(128,27),256,0,stream>>>(msg_w1,msg_w2,qw,kw,vw,ow,qb,kb,vb,
      ob,msg_b1,msg_b2,msg_g,msg_bb,attn_g,attn_b,
      enc_w1,enc_w2,enc_b1,enc_g1,enc_bn1,enc_b2,enc_g2,enc_bn2,
      gh_w1,gh_w2,gh_b1,gh_g,gh_bn,gh_b2,
      w1t,w2k,qkvt,owt,w1te,w2te,ghw1t,ghw2t,cb,flag);

  enc_kernel<<<BN_/64,256,0,stream>>>(x,w1te,w2te,cb,h,flag);

  for(int l=0;l<3;l++){
    for(int ep=0;ep<epass;ep++){
      int b0=ep*gEp;
      unsigned short* UV=(unsigned short*)R;   // gEp*512 x 256 bf16
      uvgen_kernel<<<dim3(gEp*8,2),256,0,stream>>>(h+(size_t)b0*512*128,
          w1t+(size_t)l*32768, cb+1536+l*128, UV);
      edgef_kernel<<<gEp*128,128,0,stream>>>(h,UV,ssrt,rowptr,
          w2k+(size_t)l*16384, cb+1920+l*128, cb+2304+l*128, cb+2688+l*128, b0, gEp);
    }
    for(int ap=0;ap<apass;ap++){
      int b0=ap*gA;
      unsigned short* obuf=(unsigned short*)R;
      attnf_kernel<<<gA*16,256,0,stream>>>(h, qkvt+(size_t)l*49152, cb+l*384, obuf, b0, gA);
      oproj_kernel<<<rowsA/64,256,0,stream>>>(obuf, owt+(size_t)l*16384,
          cb+1152+l*128, h, cb+3072+l*128, cb+3456+l*128, b0);
    }
  }
  poolp_kernel<<<dim3(B_,8),256,0,stream>>>(h,part);
  head_kernel<<<B_,256,0,stream>>>(part,ghw1t,ghw2t,cb,d_out,flag);
}

// Round 14
// 465.187 us; speedup vs baseline: 1.0353x; 1.0353x over previous
//
#include <hip/hip_runtime.h>
#include <cmath>

#define B_   32
#define N_   512
#define E_   8192
#define BN_  16384
#define D_   128

typedef short bf16x8 __attribute__((ext_vector_type(8)));
typedef float f32x4  __attribute__((ext_vector_type(4)));

static __device__ __forceinline__ float bf2f(unsigned short u){
  union{unsigned int i; float f;} v; v.i = ((unsigned int)u)<<16; return v.f;
}
static __device__ __forceinline__ unsigned short f2bf(float f){
  union{unsigned int i; float f;} v; v.f=f;
  unsigned int x=v.i;
  return (unsigned short)((x + 0x7fffu + ((x>>16)&1u))>>16);
}
static __device__ __forceinline__ unsigned int pack2(float a, float b){
  return (unsigned int)f2bf(a) | ((unsigned int)f2bf(b)<<16);
}
// fast GELU: A&S 7.1.26 erf, |err|<=1.5e-7 (below bf16 noise)
static __device__ __forceinline__ float gelu_f(float x){
  float xs=x*0.70710678118654752f;
  float ax=fabsf(xs);
  float t=__builtin_amdgcn_rcpf(1.0f+0.3275911f*ax);
  float p=t*(0.254829592f+t*(-0.284496736f+t*(1.421413741f+t*(-1.453152027f+t*1.061405429f))));
  float er=1.0f - p*__expf(-ax*ax);
  er = (xs<0.f)? -er : er;
  return 0.5f*x*(1.0f+er);
}
static __device__ __forceinline__ float ldin(const void* p, size_t i, int isbf){
  return isbf ? bf2f(((const unsigned short*)p)[i]) : ((const float*)p)[i];
}

static __device__ __forceinline__ void block_sum2(float a, float b, float&A, float&Bv, float* red, int nw){
  int lane=threadIdx.x&63, w=threadIdx.x>>6;
  #pragma unroll
  for(int o=32;o>0;o>>=1){ a+=__shfl_down(a,o); b+=__shfl_down(b,o); }
  if(lane==0){ red[w]=a; red[8+w]=b; }
  __syncthreads();
  float sa=0.f, sb=0.f;
  for(int i=0;i<nw;i++){ sa+=red[i]; sb+=red[8+i]; }
  __syncthreads();
  A=sa; Bv=sb;
}

// ---------------- dtype sniff ----------------
__global__ void sniff_kernel(const unsigned int* __restrict__ xw, int* __restrict__ flag){
  int t=threadIdx.x;
  int cnt=0;
  for(int i=0;i<32;i++){
    unsigned int w=xw[t+64*i];
    float v=bf2f((unsigned short)(w&0xffffu));
    float av=fabsf(v);
    if(v==0.0f || (av>=6e-5f && av<=8.0f)) cnt++;
  }
  #pragma unroll
  for(int o=32;o>0;o>>=1) cnt+=__shfl_down(cnt,o);
  if(t==0) *flag=(cnt>=1024)?1:0;
}

// ---------------- counting sort by dst + CSR rowptr ----------------
__global__ __launch_bounds__(256) void sort_kernel(
  const int* __restrict__ src, const int* __restrict__ dst,
  unsigned short* __restrict__ ss, int* __restrict__ rowptr)
{
  __shared__ int cnt[512];
  __shared__ int off[512];
  int g=blockIdx.x, t=threadIdx.x;
  for(int i=t;i<512;i+=256) cnt[i]=0;
  __syncthreads();
  for(int e=t;e<E_;e+=256) atomicAdd(&cnt[dst[g*E_+e]],1);
  __syncthreads();
  if(t==0){ int acc=0; for(int i=0;i<512;i++){ off[i]=acc; acc+=cnt[i]; } }
  __syncthreads();
  for(int i=t;i<512;i+=256) rowptr[g*513+i]=off[i];
  if(t==0) rowptr[g*513+512]=E_;
  __syncthreads();
  for(int e=t;e<E_;e+=256){
    int d=dst[g*E_+e];
    int pos=atomicAdd(&off[d],1);
    ss[g*E_+pos]=(unsigned short)src[g*E_+e];
  }
}

// cb layout (bf16 canonical):
// [0,1152) qkv bias | [1152,1536) ob | [1536,1920) msg_b1 | [1920,2304) msg_b2
// [2304,2688) msg_g | [2688,3072) msg_bb | [3072,3456) attn_g | [3456,3840) attn_b
// [3840,4096) enc_b1 | [4096,4352) enc_g1 | [4352,4608) enc_bn1
// [4608,4736) enc_b2 | [4736,4864) enc_g2 | [4864,4992) enc_bn2
// [4992,5248) gh_b1 | [5248,5504) gh_g | [5504,5760) gh_bn | [5760,5776) gh_b2
__global__ __launch_bounds__(256) void prep_kernel(
  const void* __restrict__ msg_w1, const void* __restrict__ msg_w2,
  const void* __restrict__ qw, const void* __restrict__ kw,
  const void* __restrict__ vw, const void* __restrict__ ow,
  const void* __restrict__ qb, const void* __restrict__ kb, const void* __restrict__ vb,
  const void* __restrict__ ob, const void* __restrict__ msg_b1, const void* __restrict__ msg_b2,
  const void* __restrict__ msg_g, const void* __restrict__ msg_bb,
  const void* __restrict__ attn_g, const void* __restrict__ attn_b,
  const void* __restrict__ enc_w1, const void* __restrict__ enc_w2,
  const void* __restrict__ enc_b1, const void* __restrict__ enc_g1, const void* __restrict__ enc_bn1,
  const void* __restrict__ enc_b2, const void* __restrict__ enc_g2, const void* __restrict__ enc_bn2,
  const void* __restrict__ gh_w1, const void* __restrict__ gh_w2,
  const void* __restrict__ gh_b1, const void* __restrict__ gh_g,
  const void* __restrict__ gh_bn, const void* __restrict__ gh_b2,
  unsigned short* __restrict__ w1t, unsigned short* __restrict__ w2k,
  unsigned short* __restrict__ qkvt, unsigned short* __restrict__ owt,
  unsigned short* __restrict__ w1te, unsigned short* __restrict__ w2te,
  unsigned short* __restrict__ ghw1t, unsigned short* __restrict__ ghw2t,
  unsigned short* __restrict__ cb, const int* __restrict__ flag)
{
  int isbf=*flag;
  int job=blockIdx.y;
  int i=blockIdx.x*256+threadIdx.x;
  if(job<3){ // msg_w1[l] [256][128] -> [128][256] n-major
    if(i<32768){ int l=job; int k=i>>7, n=i&127; w1t[l*32768 + n*256 + k]=f2bf(ldin(msg_w1,(size_t)l*32768+i,isbf)); }
  } else if(job<6){ // msg_w2[l] straight copy [128k][128n]
    int l=job-3; if(i<16384){ w2k[l*16384 + i]=f2bf(ldin(msg_w2,(size_t)l*16384+i,isbf)); }
  } else if(job<15){
    int r=job-6, l=r/3, which=r%3;
    if(i<16384){ int k=i>>7, n=i&127;
      const void* w=(which==0)?qw:((which==1)?kw:vw);
      qkvt[l*49152 + (which*128+n)*128 + k]=f2bf(ldin(w,(size_t)l*16384+i,isbf)); }
  } else if(job<18){
    int l=job-15; if(i<16384){ int k=i>>7, n=i&127; owt[l*16384 + n*128 + k]=f2bf(ldin(ow,(size_t)l*16384+i,isbf)); }
  } else if(job==18){
    if(i<3840){
      float v;
      if(i<1152){ int l=i/384, j=i%384, which=j>>7, jj=j&127;
        const void* bb=(which==0)?qb:((which==1)?kb:vb);
        v=ldin(bb,(size_t)l*128+jj,isbf);
      } else {
        int i2=i-1152; int r=i2/384; int rem=i2%384;
        const void* s = (r==0)?ob:((r==1)?msg_b1:((r==2)?msg_b2:((r==3)?msg_g:((r==4)?msg_bb:((r==5)?attn_g:attn_b)))));
        v=ldin(s,(size_t)rem,isbf);
      }
      cb[i]=f2bf(v);
    }
  } else if(job==19){
    if(i<1152){
      float v;
      if(i<256)       v=ldin(enc_b1,i,isbf);
      else if(i<512)  v=ldin(enc_g1,i-256,isbf);
      else if(i<768)  v=ldin(enc_bn1,i-512,isbf);
      else if(i<896)  v=ldin(enc_b2,i-768,isbf);
      else if(i<1024) v=ldin(enc_g2,i-896,isbf);
      else            v=ldin(enc_bn2,i-1024,isbf);
      cb[3840+i]=f2bf(v);
    }
  } else if(job==20){
    if(i<16384){ int k=i>>8, n=i&255; w1te[n*64+k]=f2bf(ldin(enc_w1,(size_t)i,isbf)); }
  } else if(job==21){
    if(i<32768){ int k=i>>7, n=i&127; w2te[n*256+k]=f2bf(ldin(enc_w2,(size_t)i,isbf)); }
  } else if(job<26){
    int p=job-22; int j=p*32768+i;
    if(i<32768){ int k=j>>8, n=j&255; ghw1t[n*512+k]=f2bf(ldin(gh_w1,(size_t)j,isbf)); }
  } else {
    if(i<2560){ int k=i/10, n=i%10; ghw2t[n*256+k]=f2bf(ldin(gh_w2,(size_t)i,isbf)); }
    else if(i<2560+778){
      int j=i-2560; float v;
      if(j<256)      v=ldin(gh_b1,j,isbf);
      else if(j<512) v=ldin(gh_g,j-256,isbf);
      else if(j<768) v=ldin(gh_bn,j-512,isbf);
      else           v=ldin(gh_b2,j-768,isbf);
      cb[4992+j]=f2bf(v);
    }
  }
}

// ---------------- fused node encoder ----------------
__global__ __launch_bounds__(256) void enc_kernel(
  const void* __restrict__ x, const unsigned short* __restrict__ w1te,
  const unsigned short* __restrict__ w2te, const unsigned short* __restrict__ cb,
  unsigned short* __restrict__ h, const int* __restrict__ flag)
{
  __shared__ __align__(16) unsigned short xs[64][72];
  __shared__ __align__(16) unsigned short t1[64][264];
  int isbf=*flag;
  int m0=blockIdx.x*64;
  int t=threadIdx.x, lane=t&63, w=t>>6, quad=lane>>4, ln=lane&15;
  for(int c2=t;c2<1024;c2+=256){
    int i=c2*4, row=i>>6, col=i&63;
    float v0,v1,v2,v3;
    if(isbf){
      const unsigned short* p=(const unsigned short*)x+(size_t)m0*64+i;
      v0=bf2f(p[0]); v1=bf2f(p[1]); v2=bf2f(p[2]); v3=bf2f(p[3]);
    } else {
      float4 f=*(const float4*)((const float*)x+(size_t)m0*64+i);
      v0=f.x; v1=f.y; v2=f.z; v3=f.w;
    }
    ushort4 o; o.x=f2bf(v0); o.y=f2bf(v1); o.z=f2bf(v2); o.w=f2bf(v3);
    *(ushort4*)&xs[row][col]=o;
  }
  __syncthreads();
  f32x4 a[4][4];
  #pragma unroll
  for(int nt=0;nt<4;nt++){ a[nt][0]={0,0,0,0}; a[nt][1]={0,0,0,0}; a[nt][2]={0,0,0,0}; a[nt][3]={0,0,0,0}; }
  #pragma unroll
  for(int k0i=0;k0i<2;k0i++){
    bf16x8 af[4];
    #pragma unroll
    for(int f=0;f<4;f++) af[f]=*(const bf16x8*)(&xs[f*16+ln][k0i*32+quad*8]);
    #pragma unroll
    for(int nt=0;nt<4;nt++){
      int n=w*64+nt*16+ln;
      bf16x8 bfr=*(const bf16x8*)(w1te+(size_t)n*64+k0i*32+quad*8);
      #pragma unroll
      for(int f=0;f<4;f++) a[nt][f]=__builtin_amdgcn_mfma_f32_16x16x32_bf16(af[f],bfr,a[nt][f],0,0,0);
    }
  }
  #pragma unroll
  for(int nt=0;nt<4;nt++){
    int n=w*64+nt*16+ln;
    float bv=bf2f(cb[3840+n]);
    #pragma unroll
    for(int f=0;f<4;f++)
      #pragma unroll
      for(int r=0;r<4;r++) t1[f*16+quad*4+r][n]=f2bf(a[nt][f][r]+bv);
  }
  __syncthreads();
  {
    int row=t>>2, qq=t&3;
    float s=0.f,s2=0.f;
    for(int c=qq*64;c<qq*64+64;c++){ float v=bf2f(t1[row][c]); s+=v; s2+=v*v; }
    s+=__shfl_xor(s,1); s+=__shfl_xor(s,2);
    s2+=__shfl_xor(s2,1); s2+=__shfl_xor(s2,2);
    float mu=s*(1.f/256.f), var=fmaxf(s2*(1.f/256.f)-mu*mu,0.f);
    float rr=rsqrtf(var+1e-5f);
    for(int c=qq*64;c<qq*64+64;c++){
      float v=bf2f(t1[row][c]);
      t1[row][c]=f2bf(gelu_f((v-mu)*rr*bf2f(cb[4096+c])+bf2f(cb[4352+c])));
    }
  }
  __syncthreads();
  f32x4 b2a[2][4];
  #pragma unroll
  for(int nt=0;nt<2;nt++){ b2a[nt][0]={0,0,0,0}; b2a[nt][1]={0,0,0,0}; b2a[nt][2]={0,0,0,0}; b2a[nt][3]={0,0,0,0}; }
  #pragma unroll
  for(int k0i=0;k0i<8;k0i++){
    bf16x8 af[4];
    #pragma unroll
    for(int f=0;f<4;f++) af[f]=*(const bf16x8*)(&t1[f*16+ln][k0i*32+quad*8]);
    #pragma unroll
    for(int nt=0;nt<2;nt++){
      int n=w*32+nt*16+ln;
      bf16x8 bfr=*(const bf16x8*)(w2te+(size_t)n*256+k0i*32+quad*8);
      #pragma unroll
      for(int f=0;f<4;f++) b2a[nt][f]=__builtin_amdgcn_mfma_f32_16x16x32_bf16(af[f],bfr,b2a[nt][f],0,0,0);
    }
  }
  __syncthreads();
  float* mf=(float*)&t1[0][0];   // [64][132]
  #pragma unroll
  for(int nt=0;nt<2;nt++){
    int n=w*32+nt*16+ln;
    float bv=bf2f(cb[4608+n]);
    #pragma unroll
    for(int f=0;f<4;f++)
      #pragma unroll
      for(int r=0;r<4;r++) mf[(f*16+quad*4+r)*132+n]=b2a[nt][f][r]+bv;
  }
  __syncthreads();
  {
    int row=t>>2, qq=t&3;
    float s=0.f,s2=0.f;
    for(int c=qq*32;c<qq*32+32;c++){ float v=mf[row*132+c]; s+=v; s2+=v*v; }
    s+=__shfl_xor(s,1); s+=__shfl_xor(s,2);
    s2+=__shfl_xor(s2,1); s2+=__shfl_xor(s2,2);
    float mu=s*(1.f/128.f), var=fmaxf(s2*(1.f/128.f)-mu*mu,0.f);
    float rr=rsqrtf(var+1e-5f);
    for(int c=qq*32;c<qq*32+32;c+=2){
      float v0=(mf[row*132+c  ]-mu)*rr*bf2f(cb[4736+c  ])+bf2f(cb[4864+c  ]);
      float v1=(mf[row*132+c+1]-mu)*rr*bf2f(cb[4736+c+1])+bf2f(cb[4864+c+1]);
      *(unsigned int*)(h+(size_t)(m0+row)*128+c)=pack2(v0,v1);
    }
  }
}

// ---------------- UV generation: U = h@W1a + b1, V = h@W1b ----------------
__global__ __launch_bounds__(256) void uvgen_kernel(
  const unsigned short* __restrict__ hrows, const unsigned short* __restrict__ w1t,
  const unsigned short* __restrict__ b1, unsigned short* __restrict__ UV)
{
  __shared__ __align__(16) unsigned short a_t[64][136];
  int t=threadIdx.x;
  int m0=blockIdx.x*64;
  int y=blockIdx.y;
  for(int c=t;c<1024;c+=256){
    int m=c>>4, pp=c&15;
    *(uint4*)&a_t[m][pp*8]=*((const uint4*)(hrows+(size_t)(m0+m)*128)+pp);
  }
  __syncthreads();
  int lane=t&63, w=t>>6, quad=lane>>4, ln=lane&15;
  #pragma unroll
  for(int nt=0;nt<2;nt++){
    int n=w*32+nt*16+ln;
    f32x4 a0={0,0,0,0},a1={0,0,0,0},a2={0,0,0,0},a3={0,0,0,0};
    const unsigned short* wp=w1t+(size_t)n*256+y*128+quad*8;
    #pragma unroll
    for(int k0=0;k0<128;k0+=32){
      bf16x8 bfr=*(const bf16x8*)(wp+k0);
      bf16x8 f0=*(const bf16x8*)(&a_t[ln   ][k0+quad*8]);
      bf16x8 f1=*(const bf16x8*)(&a_t[16+ln][k0+quad*8]);
      bf16x8 f2=*(const bf16x8*)(&a_t[32+ln][k0+quad*8]);
      bf16x8 f3=*(const bf16x8*)(&a_t[48+ln][k0+quad*8]);
      a0=__builtin_amdgcn_mfma_f32_16x16x32_bf16(f0,bfr,a0,0,0,0);
      a1=__builtin_amdgcn_mfma_f32_16x16x32_bf16(f1,bfr,a1,0,0,0);
      a2=__builtin_amdgcn_mfma_f32_16x16x32_bf16(f2,bfr,a2,0,0,0);
      a3=__builtin_amdgcn_mfma_f32_16x16x32_bf16(f3,bfr,a3,0,0,0);
    }
    float bv=y?0.f:bf2f(b1[n]);
    #pragma unroll
    for(int r2=0;r2<4;r2++){
      UV[(size_t)(m0+quad*4+r2   )*256+y*128+n]=f2bf(a0[r2]+bv);
      UV[(size_t)(m0+16+quad*4+r2)*256+y*128+n]=f2bf(a1[r2]+bv);
      UV[(size_t)(m0+32+quad*4+r2)*256+y*128+n]=f2bf(a2[r2]+bv);
      UV[(size_t)(m0+48+quad*4+r2)*256+y*128+n]=f2bf(a3[r2]+bv);
    }
  }
}

// ---------------- fused edge phase: branchless gather + k-split GEMV; XCD-local swizzle ----------------
// blockDim=128. Wave w gathers half of each dst's edges (branchless: over-reads masked &511);
// GEMV k-split: each wave does all 4 dst over half k (8 FMA/load, W2 traffic halved);
// partials combined via LDS po, wave w finalizes dst pair {2w,2w+1}.
__global__ __launch_bounds__(128) void edgef_kernel(
  unsigned short* __restrict__ h,
  const unsigned short* __restrict__ UV,      // local rows [gEp*512][256]
  const unsigned short* __restrict__ ss,
  const int* __restrict__ rowptr,
  const unsigned short* __restrict__ w2k,     // [128k][128n]
  const unsigned short* __restrict__ b2,
  const unsigned short* __restrict__ gg, const unsigned short* __restrict__ bbp,
  int b0, int gEp)
{
  __shared__ __align__(16) float aggL[2][4][128];
  __shared__ __align__(16) float po[2][4][128];
  int t=threadIdx.x, lane=t&63, w=t>>6;
  int bid=blockIdx.x;
  int lg=bid%gEp, ch=bid/gEp;     // ch in [0,128): 4-dst chunk
  int g=b0+lg;
  const unsigned short* UVg = UV + (size_t)lg*512*256;
  const unsigned short* ssg = ss + (size_t)g*E_;
  int dbase = ch*4;
  int bnd[5];
  #pragma unroll
  for(int i=0;i<5;i++) bnd[i]=rowptr[g*513+dbase+i];
  // ---- gather: wave w takes its half of each dst's edge range (branchless, masked idx) ----
  #pragma unroll 1
  for(int dd=0;dd<4;dd++){
    int e_lo=bnd[dd], e_hi0=bnd[dd+1];
    int half=(e_hi0-e_lo+1)>>1;
    int es = w ? (e_lo+half) : e_lo;
    int ee = w ? e_hi0       : (e_lo+half);
    unsigned int vdw=*(const unsigned int*)(UVg + (size_t)(dbase+dd)*256 + 128 + lane*2);
    float v0=bf2f((unsigned short)(vdw&0xffffu)), v1=bf2f((unsigned short)(vdw>>16));
    float a0=0.f, a1=0.f;
    int si3,si4,si5;
    unsigned int u0,u1,u2;
    {
      // over-reads (<=6 u16 past range) stay inside ss / start of R (in-ws); idx masked &511
      int s0=__builtin_amdgcn_readfirstlane((int)ssg[es  ])&511;
      int s1=__builtin_amdgcn_readfirstlane((int)ssg[es+1])&511;
      int s2=__builtin_amdgcn_readfirstlane((int)ssg[es+2])&511;
      si3=(int)ssg[es+3]; si4=(int)ssg[es+4]; si5=(int)ssg[es+5];
      u0=*(const unsigned int*)(UVg + (size_t)s0*256 + lane*2);
      u1=*(const unsigned int*)(UVg + (size_t)s1*256 + lane*2);
      u2=*(const unsigned int*)(UVg + (size_t)s2*256 + lane*2);
    }
    #pragma unroll 1
    for(int e=es;e<ee;e++){
      float z0=bf2f((unsigned short)(u0&0xffffu))+v0;
      float z1=bf2f((unsigned short)(u0>>16))+v1;
      u0=u1; u1=u2;
      int s3=__builtin_amdgcn_readfirstlane(si3)&511;
      u2=*(const unsigned int*)(UVg + (size_t)s3*256 + lane*2);
      si3=si4; si4=si5;
      si5=(int)ssg[e+6];
      a0+=gelu_f(z0); a1+=gelu_f(z1);
    }
    aggL[w][dd][lane*2  ]=a0;
    aggL[w][dd][lane*2+1]=a1;
  }
  __syncthreads();
  // ---- GEMV k-split: wave w does all 4 dst over k in [w*64, w*64+64) ----
  float o[4][2];
  #pragma unroll
  for(int dd=0;dd<4;dd++){ o[dd][0]=0.f; o[dd][1]=0.f; }
  #pragma unroll 4
  for(int kk=0;kk<64;kk++){
    int k=w*64+kk;
    unsigned int wdw=*(const unsigned int*)(w2k+(size_t)k*128+lane*2);
    float w0=bf2f((unsigned short)(wdw&0xffffu));
    float w1=bf2f((unsigned short)(wdw>>16));
    #pragma unroll
    for(int dd=0;dd<4;dd++){
      float av=aggL[0][dd][k]+aggL[1][dd][k];
      o[dd][0]+=av*w0; o[dd][1]+=av*w1;
    }
  }
  #pragma unroll
  for(int dd=0;dd<4;dd++){
    po[w][dd][lane*2  ]=o[dd][0];
    po[w][dd][lane*2+1]=o[dd][1];
  }
  __syncthreads();
  // ---- combine partials + deg*b2 + residual + LN: wave w owns dst pair {2w, 2w+1} ----
  #pragma unroll 1
  for(int p=0;p<2;p++){
    int di=w*2+p;
    int d = dbase + di;
    float deg=(float)(bnd[di+1]-bnd[di]);
    float o0=bf2f(b2[lane*2  ])*deg + po[0][di][lane*2  ] + po[1][di][lane*2  ];
    float o1=bf2f(b2[lane*2+1])*deg + po[0][di][lane*2+1] + po[1][di][lane*2+1];
    size_t base=(size_t)(g*512+d)*128;
    unsigned int hdw=*(const unsigned int*)(h+base+lane*2);
    float x0=bf2f((unsigned short)(hdw&0xffffu))+o0;
    float x1=bf2f((unsigned short)(hdw>>16))+o1;
    float s1=x0+x1, s2=x0*x0+x1*x1;
    #pragma unroll
    for(int off=32;off>0;off>>=1){ s1+=__shfl_xor(s1,off); s2+=__shfl_xor(s2,off); }
    float mu=s1*(1.f/128.f), var=fmaxf(s2*(1.f/128.f)-mu*mu,0.f);
    float rr=rsqrtf(var+1e-5f);
    float y0=(x0-mu)*rr*bf2f(gg[lane*2  ])+bf2f(bbp[lane*2  ]);
    float y1=(x1-mu)*rr*bf2f(gg[lane*2+1])+bf2f(bbp[lane*2+1]);
    *(unsigned int*)(h+base+lane*2)=pack2(y0,y1);
  }
}

// ---------------- fused QKV + flash attention: per (graph, head, q-QUARTER), XCD-local swizzle ----------------
__global__ __launch_bounds__(256) void attnf_kernel(
  const unsigned short* __restrict__ h, const unsigned short* __restrict__ wqkv,
  const unsigned short* __restrict__ bq, unsigned short* __restrict__ obuf, int b0, int gA)
{
  __shared__ __align__(16) unsigned short Qs[128][40];
  __shared__ __align__(16) unsigned short Ks[64][72];
  __shared__ __align__(16) unsigned short Vts[32][72];
  __shared__ __align__(16) unsigned short Ps[64][72];
  int bx=blockIdx.x;
  int lg=bx%gA; int rr2=bx/gA; int hh=rr2&3, qq4=rr2>>2;
  int g=b0+lg;
  int t=threadIdx.x, lane=t&63, w=t>>6, quad=lane>>4, ln=lane&15;
  const unsigned short* hg=h+(size_t)g*512*128;
  const float sc=0.17677669529663689f;
  bf16x8 wk[2][4], wv[2][4];
  #pragma unroll
  for(int nt=0;nt<2;nt++)
    #pragma unroll
    for(int k0i=0;k0i<4;k0i++){
      int n=hh*32+nt*16+ln;
      wk[nt][k0i]=*(const bf16x8*)(wqkv+(size_t)(128+n)*128+k0i*32+quad*8);
      wv[nt][k0i]=*(const bf16x8*)(wqkv+(size_t)(256+n)*128+k0i*32+quad*8);
    }
  #pragma unroll
  for(int qt=0;qt<2;qt++){
    int r0=qq4*128+qt*64+w*16;
    bf16x8 af[4];
    #pragma unroll
    for(int k0i=0;k0i<4;k0i++) af[k0i]=*(const bf16x8*)(hg+(size_t)(r0+ln)*128+k0i*32+quad*8);
    #pragma unroll
    for(int nt=0;nt<2;nt++){
      int dim=nt*16+ln;
      f32x4 c={0,0,0,0};
      #pragma unroll
      for(int k0i=0;k0i<4;k0i++){
        bf16x8 bfr=*(const bf16x8*)(wqkv+(size_t)(hh*32+dim)*128+k0i*32+quad*8);
        c=__builtin_amdgcn_mfma_f32_16x16x32_bf16(af[k0i],bfr,c,0,0,0);
      }
      float bv=bf2f(bq[hh*32+dim]);
      #pragma unroll
      for(int r=0;r<4;r++) Qs[qt*64+w*16+quad*4+r][dim]=f2bf((c[r]+bv)*sc);
    }
  }
  f32x4 O[2][2]; float Lp[2][4];
  #pragma unroll
  for(int qt=0;qt<2;qt++){ O[qt][0]={0,0,0,0}; O[qt][1]={0,0,0,0};
    #pragma unroll
    for(int r=0;r<4;r++) Lp[qt][r]=0.f; }
  for(int kc=0;kc<8;kc++){
    __syncthreads();
    {
      int r0=kc*64+w*16;
      bf16x8 af[4];
      #pragma unroll
      for(int k0i=0;k0i<4;k0i++) af[k0i]=*(const bf16x8*)(hg+(size_t)(r0+ln)*128+k0i*32+quad*8);
      #pragma unroll
      for(int nt=0;nt<2;nt++){
        int dim=nt*16+ln;
        f32x4 ck={0,0,0,0}, cv={0,0,0,0};
        #pragma unroll
        for(int k0i=0;k0i<4;k0i++){
          ck=__builtin_amdgcn_mfma_f32_16x16x32_bf16(af[k0i],wk[nt][k0i],ck,0,0,0);
          cv=__builtin_amdgcn_mfma_f32_16x16x32_bf16(af[k0i],wv[nt][k0i],cv,0,0,0);
        }
        float bk=bf2f(bq[128+hh*32+dim]), bv2=bf2f(bq[256+hh*32+dim]);
        #pragma unroll
        for(int r=0;r<4;r++){
          int key=w*16+quad*4+r;
          Ks[key][dim]=f2bf(ck[r]+bk);
          Vts[dim][key]=f2bf(cv[r]+bv2);
        }
      }
    }
    __syncthreads();
    #pragma unroll
    for(int qt=0;qt<2;qt++){
      bf16x8 qf=*(const bf16x8*)(&Qs[qt*64+w*16+ln][quad*8]);
      f32x4 s[4];
      #pragma unroll
      for(int f=0;f<4;f++){
        bf16x8 kf=*(const bf16x8*)(&Ks[f*16+ln][quad*8]);
        f32x4 z={0,0,0,0};
        s[f]=__builtin_amdgcn_mfma_f32_16x16x32_bf16(qf,kf,z,0,0,0);
      }
      #pragma unroll
      for(int f=0;f<4;f++)
        #pragma unroll
        for(int r=0;r<4;r++){
          float pe=__expf(fminf(s[f][r],30.0f));
          Ps[w*16+quad*4+r][f*16+ln]=f2bf(pe);
          Lp[qt][r]+=pe;
        }
      #pragma unroll
      for(int s2=0;s2<2;s2++){
        bf16x8 pf=*(const bf16x8*)(&Ps[w*16+ln][s2*32+quad*8]);
        bf16x8 v0=*(const bf16x8*)(&Vts[ln   ][s2*32+quad*8]);
        bf16x8 v1=*(const bf16x8*)(&Vts[16+ln][s2*32+quad*8]);
        O[qt][0]=__builtin_amdgcn_mfma_f32_16x16x32_bf16(pf,v0,O[qt][0],0,0,0);
        O[qt][1]=__builtin_amdgcn_mfma_f32_16x16x32_bf16(pf,v1,O[qt][1],0,0,0);
      }
    }
  }
  #pragma unroll
  for(int qt=0;qt<2;qt++){
    #pragma unroll
    for(int o=1;o<16;o<<=1)
      #pragma unroll
      for(int r=0;r<4;r++) Lp[qt][r]+=__shfl_xor(Lp[qt][r],o);
    #pragma unroll
    for(int r=0;r<4;r++){
      float inv=1.0f/Lp[qt][r];
      size_t row=(size_t)lg*512+qq4*128+qt*64+w*16+quad*4+r;
      obuf[row*128+hh*32+ln   ]=f2bf(O[qt][0][r]*inv);
      obuf[row*128+hh*32+16+ln]=f2bf(O[qt][1][r]*inv);
    }
  }
}

// ---------------- oproj + residual + LN ----------------
__global__ __launch_bounds__(256) void oproj_kernel(
  const unsigned short* __restrict__ obuf, const unsigned short* __restrict__ wo,
  const unsigned short* __restrict__ bo, unsigned short* __restrict__ h,
  const unsigned short* __restrict__ gg, const unsigned short* __restrict__ bbp, int b0)
{
  __shared__ __align__(16) unsigned short a_t[64][136];
  __shared__ float mf[64][132];
  int t=threadIdx.x, lane=t&63, w=t>>6, quad=lane>>4, ln=lane&15;
  int m0=blockIdx.x*64;
  for(int c=t;c<64*16;c+=256){
    int m=c>>4, pp=c&15;
    *(uint4*)&a_t[m][pp*8]=*((const uint4*)(obuf+(size_t)(m0+m)*128)+pp);
  }
  __syncthreads();
  #pragma unroll
  for(int nt=0;nt<2;nt++){
    int n=w*32+nt*16+ln;
    f32x4 a0={0,0,0,0},a1={0,0,0,0},a2={0,0,0,0},a3={0,0,0,0};
    const unsigned short* wp=wo+(size_t)n*128+quad*8;
    #pragma unroll
    for(int k0=0;k0<128;k0+=32){
      bf16x8 bfr=*(const bf16x8*)(wp+k0);
      bf16x8 f0=*(const bf16x8*)(&a_t[ln   ][k0+quad*8]);
      bf16x8 f1=*(const bf16x8*)(&a_t[16+ln][k0+quad*8]);
      bf16x8 f2=*(const bf16x8*)(&a_t[32+ln][k0+quad*8]);
      bf16x8 f3=*(const bf16x8*)(&a_t[48+ln][k0+quad*8]);
      a0=__builtin_amdgcn_mfma_f32_16x16x32_bf16(f0,bfr,a0,0,0,0);
      a1=__builtin_amdgcn_mfma_f32_16x16x32_bf16(f1,bfr,a1,0,0,0);
      a2=__builtin_amdgcn_mfma_f32_16x16x32_bf16(f2,bfr,a2,0,0,0);
      a3=__builtin_amdgcn_mfma_f32_16x16x32_bf16(f3,bfr,a3,0,0,0);
    }
    float bv=bf2f(bo[n]);
    #pragma unroll
    for(int r=0;r<4;r++){
      mf[quad*4+r   ][n]=a0[r]+bv;
      mf[16+quad*4+r][n]=a1[r]+bv;
      mf[32+quad*4+r][n]=a2[r]+bv;
      mf[48+quad*4+r][n]=a3[r]+bv;
    }
  }
  __syncthreads();
  {
    int row=t>>2, qq=t&3;
    size_t base=(size_t)(b0*512+m0+row)*128;
    float s=0.f,s2=0.f;
    float vals[32];
    for(int j=0;j<32;j++){
      int c=qq*32+j;
      float v=bf2f(h[base+c])+mf[row][c];
      vals[j]=v; s+=v; s2+=v*v;
    }
    s+=__shfl_xor(s,1); s+=__shfl_xor(s,2);
    s2+=__shfl_xor(s2,1); s2+=__shfl_xor(s2,2);
    float mu=s*(1.f/128.f), var=fmaxf(s2*(1.f/128.f)-mu*mu,0.f);
    float rr=rsqrtf(var+1e-5f);
    for(int j=0;j<32;j+=2){
      int c=qq*32+j;
      float v0=(vals[j]  -mu)*rr*bf2f(gg[c  ])+bf2f(bbp[c  ]);
      float v1=(vals[j+1]-mu)*rr*bf2f(gg[c+1])+bf2f(bbp[c+1]);
      *(unsigned int*)(h+base+c)=pack2(v0,v1);
    }
  }
}

// ---------------- pooling partials ----------------
__global__ __launch_bounds__(256) void poolp_kernel(
  const unsigned short* __restrict__ h, float* __restrict__ part)
{
  __shared__ float ps[256], ps2[256], pm[256];
  int b=blockIdx.x, c=blockIdx.y;
  int t=threadIdx.x, d=t&127, hf=t>>7;
  float s=0.f,s2=0.f,mx=-1e30f;
  for(int r=hf*32;r<hf*32+32;r++){
    float v=bf2f(h[((size_t)(b*512+c*64+r))*128+d]);
    s+=v; s2+=v*v; mx=fmaxf(mx,v);
  }
  ps[t]=s; ps2[t]=s2; pm[t]=mx;
  __syncthreads();
  if(t<128){
    s=ps[t]+ps[128+t]; s2=ps2[t]+ps2[128+t]; mx=fmaxf(pm[t],pm[128+t]);
    size_t base=((size_t)(b*8+c))*384;
    part[base+t]=s; part[base+128+t]=s2; part[base+256+t]=mx;
  }
}

// ---------------- graph head: finalize pooling + MLP ----------------
__global__ __launch_bounds__(256) void head_kernel(
  const float* __restrict__ part, const unsigned short* __restrict__ ghw1t,
  const unsigned short* __restrict__ ghw2t, const unsigned short* __restrict__ cb,
  void* __restrict__ out, const int* __restrict__ flag)
{
  int isbf=*flag;
  int b=blockIdx.x, t=threadIdx.x;
  __shared__ float pl[512];
  __shared__ float gl[256];
  __shared__ float red[16];
  if(t<128){
    float s=0.f,s2=0.f,mx=-1e30f;
    for(int c=0;c<8;c++){
      size_t base=((size_t)(b*8+c))*384;
      s += part[base+t];
      s2+= part[base+128+t];
      mx = fmaxf(mx, part[base+256+t]);
    }
    float mean=s*(1.f/512.f);
    float var=fmaxf(s2*(1.f/512.f)-mean*mean,0.f);
    float sd=sqrtf(var+1e-6f);
    pl[t]=mean; pl[128+t]=s; pl[256+t]=mx; pl[384+t]=sd;
  }
  __syncthreads();
  float a=bf2f(cb[4992+t]);
  const unsigned short* wr=ghw1t+(size_t)t*512;
  for(int k0=0;k0<512;k0+=8){
    bf16x8 wv=*(const bf16x8*)(wr+k0);
    const unsigned short* wp=(const unsigned short*)&wv;
    #pragma unroll
    for(int j=0;j<8;j++) a+=pl[k0+j]*bf2f(wp[j]);
  }
  float u=gelu_f(a);
  float S,S2; block_sum2(u,u*u,S,S2,red,4);
  float mu=S*(1.f/256.f), var=fmaxf(S2*(1.f/256.f)-mu*mu,0.f);
  float r=rsqrtf(var+1e-5f);
  gl[t]=(u-mu)*r*bf2f(cb[5248+t])+bf2f(cb[5504+t]);
  __syncthreads();
  if(t<10){
    float o=bf2f(cb[5760+t]);
    const unsigned short* wr2=ghw2t+(size_t)t*256;
    for(int k0=0;k0<256;k0+=8){
      bf16x8 wv=*(const bf16x8*)(wr2+k0);
      const unsigned short* wp=(const unsigned short*)&wv;
      #pragma unroll
      for(int j=0;j<8;j++) o+=gl[k0+j]*bf2f(wp[j]);
    }
    if(isbf) ((unsigned short*)out)[b*10+t]=f2bf(o);
    else     ((float*)out)[b*10+t]=o;
  }
}

extern "C" void kernel_launch(void* const* d_in, const int* in_sizes, int n_in,
                              void* d_out, int out_size, void* d_ws, size_t ws_size,
                              hipStream_t stream)
{
  const void* x      =d_in[0];
  const int*  src    =(const int*)d_in[1];
  const int*  dstp   =(const int*)d_in[2];
  const void* enc_w1 =d_in[3];  const void* enc_b1 =d_in[4];
  const void* enc_g1 =d_in[5];  const void* enc_bn1=d_in[6];
  const void* enc_w2 =d_in[7];  const void* enc_b2 =d_in[8];
  const void* enc_g2 =d_in[9];  const void* enc_bn2=d_in[10];
  const void* msg_w1 =d_in[11]; const void* msg_b1 =d_in[12];
  const void* msg_w2 =d_in[13]; const void* msg_b2 =d_in[14];
  const void* msg_g  =d_in[15]; const void* msg_bb =d_in[16];
  const void* qw     =d_in[17]; const void* qb     =d_in[18];
  const void* kw     =d_in[19]; const void* kb     =d_in[20];
  const void* vw     =d_in[21]; const void* vb     =d_in[22];
  const void* ow     =d_in[23]; const void* ob     =d_in[24];
  const void* attn_g =d_in[25]; const void* attn_b =d_in[26];
  const void* gh_w1  =d_in[27]; const void* gh_b1  =d_in[28];
  const void* gh_g   =d_in[29]; const void* gh_bn  =d_in[30];
  const void* gh_w2  =d_in[31]; const void* gh_b2  =d_in[32];
  (void)in_sizes; (void)n_in; (void)out_size;

  const size_t MB=1024*1024;
  char* base=(char*)d_ws;
  unsigned short* h    =(unsigned short*)(base);                 // 4 MB
  unsigned short* w1t  =(unsigned short*)(base + 4194304);
  unsigned short* w2k  =(unsigned short*)(base + 4390912);
  unsigned short* qkvt =(unsigned short*)(base + 4489216);
  unsigned short* owt  =(unsigned short*)(base + 4784128);
  unsigned short* w1te =(unsigned short*)(base + 4882432);
  unsigned short* w2te =(unsigned short*)(base + 4915200);
  unsigned short* ghw1t=(unsigned short*)(base + 4980736);
  unsigned short* ghw2t=(unsigned short*)(base + 5242880);
  unsigned short* cb   =(unsigned short*)(base + 5248000);
  int*   rowptr        =(int*)(base + 5325312);
  int*   flag          =(int*)(base + 5390976);
  unsigned short* ssrt =(unsigned short*)(base + 5505024);       // 512 KB (+edgef over-reads land in R)
  char* R              = base + 6029312;                          // shared region

  int epass, apass;
  if(ws_size >= (size_t)(14.5*MB)){ epass=1; apass=1; }
  else if(ws_size >= 10*MB){ epass=2; apass=1; }
  else { epass=4; apass=2; }
  int gEp=B_/epass, gA=B_/apass;
  int rowsA=gA*512;
  float* part=(float*)R;   // pool partials: 32*8*384*4 = 393 KB (R free after layer loop)

  sniff_kernel<<<1,64,0,stream>>>((const unsigned int*)x, flag);
  sort_kernel<<<B_,256,0,stream>>>(src,dstp,ssrt,rowptr);
  prep_kernel<<<dim3(128,27),256,0,stream>>>(msg_w1,msg_w2,qw,kw,vw,ow,qb,kb,vb,
      ob,msg_b1,msg_b2,msg_g,msg_bb,attn_g,attn_b,
      enc_w1,enc_w2,enc_b1,enc_g1,enc_bn1,enc_b2,enc_g2,enc_bn2,
      gh_w1,gh_w2,gh_b1,gh_g,gh_bn,gh_b2,
      w1t,w2k,qkvt,owt,w1te,w2te,ghw1t,ghw2t,cb,flag);

  enc_kernel<<<BN_/64,256,0,stream>>>(x,w1te,w2te,cb,h,flag);

  for(int l=0;l<3;l++){
    for(int ep=0;ep<epass;ep++){
      int b0=ep*gEp;
      unsigned short* UV=(unsigned short*)R;   // gEp*512 x 256 bf16
      uvgen_kernel<<<dim3(gEp*8,2),256,0,stream>>>(h+(size_t)b0*512*128,
          w1t+(size_t)l*32768, cb+1536+l*128, UV);
      edgef_kernel<<<gEp*128,128,0,stream>>>(h,UV,ssrt,rowptr,
          w2k+(size_t)l*16384, cb+1920+l*128, cb+2304+l*128, cb+2688+l*128, b0, gEp);
    }
    for(int ap=0;ap<apass;ap++){
      int b0=ap*gA;
      unsigned short* obuf=(unsigned short*)R;
      attnf_kernel<<<gA*16,256,0,stream>>>(h, qkvt+(size_t)l*49152, cb+l*384, obuf, b0, gA);
      oproj_kernel<<<rowsA/64,256,0,stream>>>(obuf, owt+(size_t)l*16384,
          cb+1152+l*128, h, cb+3072+l*128, cb+3456+l*128, b0);
    }
  }
  poolp_kernel<<<dim3(B_,8),256,0,stream>>>(h,part);
  head_kernel<<<B_,256,0,stream>>>(part,ghw1t,ghw2t,cb,d_out,flag);
}

// Round 15
// 456.016 us; speedup vs baseline: 1.0561x; 1.0201x over previous
//
#include <hip/hip_runtime.h>
#include <cmath>

#define B_   32
#define N_   512
#define E_   8192
#define BN_  16384
#define D_   128

typedef short bf16x8 __attribute__((ext_vector_type(8)));
typedef float f32x4  __attribute__((ext_vector_type(4)));

static __device__ __forceinline__ float bf2f(unsigned short u){
  union{unsigned int i; float f;} v; v.i = ((unsigned int)u)<<16; return v.f;
}
static __device__ __forceinline__ unsigned short f2bf(float f){
  union{unsigned int i; float f;} v; v.f=f;
  unsigned int x=v.i;
  return (unsigned short)((x + 0x7fffu + ((x>>16)&1u))>>16);
}
static __device__ __forceinline__ unsigned int pack2(float a, float b){
  return (unsigned int)f2bf(a) | ((unsigned int)f2bf(b)<<16);
}
// fast GELU: A&S 7.1.26 erf, |err|<=1.5e-7 (below bf16 noise)
static __device__ __forceinline__ float gelu_f(float x){
  float xs=x*0.70710678118654752f;
  float ax=fabsf(xs);
  float t=__builtin_amdgcn_rcpf(1.0f+0.3275911f*ax);
  float p=t*(0.254829592f+t*(-0.284496736f+t*(1.421413741f+t*(-1.453152027f+t*1.061405429f))));
  float er=1.0f - p*__expf(-ax*ax);
  er = (xs<0.f)? -er : er;
  return 0.5f*x*(1.0f+er);
}
static __device__ __forceinline__ float ldin(const void* p, size_t i, int isbf){
  return isbf ? bf2f(((const unsigned short*)p)[i]) : ((const float*)p)[i];
}

static __device__ __forceinline__ void block_sum2(float a, float b, float&A, float&Bv, float* red, int nw){
  int lane=threadIdx.x&63, w=threadIdx.x>>6;
  #pragma unroll
  for(int o=32;o>0;o>>=1){ a+=__shfl_down(a,o); b+=__shfl_down(b,o); }
  if(lane==0){ red[w]=a; red[8+w]=b; }
  __syncthreads();
  float sa=0.f, sb=0.f;
  for(int i=0;i<nw;i++){ sa+=red[i]; sb+=red[8+i]; }
  __syncthreads();
  A=sa; Bv=sb;
}

// ---------------- dtype sniff ----------------
__global__ void sniff_kernel(const unsigned int* __restrict__ xw, int* __restrict__ flag){
  int t=threadIdx.x;
  int cnt=0;
  for(int i=0;i<32;i++){
    unsigned int w=xw[t+64*i];
    float v=bf2f((unsigned short)(w&0xffffu));
    float av=fabsf(v);
    if(v==0.0f || (av>=6e-5f && av<=8.0f)) cnt++;
  }
  #pragma unroll
  for(int o=32;o>0;o>>=1) cnt+=__shfl_down(cnt,o);
  if(t==0) *flag=(cnt>=1024)?1:0;
}

// ---------------- parallel 3-stage counting sort by dst ----------------
__global__ __launch_bounds__(256) void count_kernel(
  const int* __restrict__ dst, int* __restrict__ cnt)
{
  __shared__ int lc[512];
  int g=blockIdx.x, c=blockIdx.y, t=threadIdx.x;
  for(int i=t;i<512;i+=256) lc[i]=0;
  __syncthreads();
  for(int e=t;e<1024;e+=256) atomicAdd(&lc[dst[(size_t)g*E_+c*1024+e]],1);
  __syncthreads();
  for(int i=t;i<512;i+=256){ int v=lc[i]; if(v) atomicAdd(&cnt[g*512+i],v); }
}

__global__ __launch_bounds__(256) void scan_kernel(
  int* __restrict__ cnt, int* __restrict__ rowptr)
{
  __shared__ int sc[512];
  int g=blockIdx.x, t=threadIdx.x;
  for(int i=t;i<512;i+=256) sc[i]=cnt[g*512+i];
  __syncthreads();
  if(t==0){
    int acc=0;
    for(int i=0;i<512;i++){ int c=sc[i]; rowptr[g*513+i]=acc; cnt[g*512+i]=acc; acc+=c; }
    rowptr[g*513+512]=acc;
  }
}

__global__ __launch_bounds__(256) void scatter_kernel(
  const int* __restrict__ src, const int* __restrict__ dst,
  int* __restrict__ off, unsigned short* __restrict__ ss)
{
  int g=blockIdx.x, c=blockIdx.y, t=threadIdx.x;
  for(int e=t;e<1024;e+=256){
    size_t idx=(size_t)g*E_+c*1024+e;
    int d=dst[idx];
    int pos=atomicAdd(&off[g*512+d],1);
    ss[(size_t)g*E_+pos]=(unsigned short)src[idx];
  }
}

// cb layout (bf16 canonical):
// [0,1152) qkv bias | [1152,1536) ob | [1536,1920) msg_b1 | [1920,2304) msg_b2
// [2304,2688) msg_g | [2688,3072) msg_bb | [3072,3456) attn_g | [3456,3840) attn_b
// [3840,4096) enc_b1 | [4096,4352) enc_g1 | [4352,4608) enc_bn1
// [4608,4736) enc_b2 | [4736,4864) enc_g2 | [4864,4992) enc_bn2
// [4992,5248) gh_b1 | [5248,5504) gh_g | [5504,5760) gh_bn | [5760,5776) gh_b2
__global__ __launch_bounds__(256) void prep_kernel(
  const void* __restrict__ msg_w1, const void* __restrict__ msg_w2,
  const void* __restrict__ qw, const void* __restrict__ kw,
  const void* __restrict__ vw, const void* __restrict__ ow,
  const void* __restrict__ qb, const void* __restrict__ kb, const void* __restrict__ vb,
  const void* __restrict__ ob, const void* __restrict__ msg_b1, const void* __restrict__ msg_b2,
  const void* __restrict__ msg_g, const void* __restrict__ msg_bb,
  const void* __restrict__ attn_g, const void* __restrict__ attn_b,
  const void* __restrict__ enc_w1, const void* __restrict__ enc_w2,
  const void* __restrict__ enc_b1, const void* __restrict__ enc_g1, const void* __restrict__ enc_bn1,
  const void* __restrict__ enc_b2, const void* __restrict__ enc_g2, const void* __restrict__ enc_bn2,
  const void* __restrict__ gh_w1, const void* __restrict__ gh_w2,
  const void* __restrict__ gh_b1, const void* __restrict__ gh_g,
  const void* __restrict__ gh_bn, const void* __restrict__ gh_b2,
  unsigned short* __restrict__ w1t, unsigned short* __restrict__ w2k,
  unsigned short* __restrict__ qkvt, unsigned short* __restrict__ owt,
  unsigned short* __restrict__ w1te, unsigned short* __restrict__ w2te,
  unsigned short* __restrict__ ghw1t, unsigned short* __restrict__ ghw2t,
  unsigned short* __restrict__ cb, const int* __restrict__ flag)
{
  int isbf=*flag;
  int job=blockIdx.y;
  int i=blockIdx.x*256+threadIdx.x;
  if(job<3){ // msg_w1[l] [256][128] -> [128][256] n-major
    if(i<32768){ int l=job; int k=i>>7, n=i&127; w1t[l*32768 + n*256 + k]=f2bf(ldin(msg_w1,(size_t)l*32768+i,isbf)); }
  } else if(job<6){ // msg_w2[l] straight copy [128k][128n]
    int l=job-3; if(i<16384){ w2k[l*16384 + i]=f2bf(ldin(msg_w2,(size_t)l*16384+i,isbf)); }
  } else if(job<15){
    int r=job-6, l=r/3, which=r%3;
    if(i<16384){ int k=i>>7, n=i&127;
      const void* w=(which==0)?qw:((which==1)?kw:vw);
      qkvt[l*49152 + (which*128+n)*128 + k]=f2bf(ldin(w,(size_t)l*16384+i,isbf)); }
  } else if(job<18){
    int l=job-15; if(i<16384){ int k=i>>7, n=i&127; owt[l*16384 + n*128 + k]=f2bf(ldin(ow,(size_t)l*16384+i,isbf)); }
  } else if(job==18){
    if(i<3840){
      float v;
      if(i<1152){ int l=i/384, j=i%384, which=j>>7, jj=j&127;
        const void* bb=(which==0)?qb:((which==1)?kb:vb);
        v=ldin(bb,(size_t)l*128+jj,isbf);
      } else {
        int i2=i-1152; int r=i2/384; int rem=i2%384;
        const void* s = (r==0)?ob:((r==1)?msg_b1:((r==2)?msg_b2:((r==3)?msg_g:((r==4)?msg_bb:((r==5)?attn_g:attn_b)))));
        v=ldin(s,(size_t)rem,isbf);
      }
      cb[i]=f2bf(v);
    }
  } else if(job==19){
    if(i<1152){
      float v;
      if(i<256)       v=ldin(enc_b1,i,isbf);
      else if(i<512)  v=ldin(enc_g1,i-256,isbf);
      else if(i<768)  v=ldin(enc_bn1,i-512,isbf);
      else if(i<896)  v=ldin(enc_b2,i-768,isbf);
      else if(i<1024) v=ldin(enc_g2,i-896,isbf);
      else            v=ldin(enc_bn2,i-1024,isbf);
      cb[3840+i]=f2bf(v);
    }
  } else if(job==20){
    if(i<16384){ int k=i>>8, n=i&255; w1te[n*64+k]=f2bf(ldin(enc_w1,(size_t)i,isbf)); }
  } else if(job==21){
    if(i<32768){ int k=i>>7, n=i&127; w2te[n*256+k]=f2bf(ldin(enc_w2,(size_t)i,isbf)); }
  } else if(job<26){
    int p=job-22; int j=p*32768+i;
    if(i<32768){ int k=j>>8, n=j&255; ghw1t[n*512+k]=f2bf(ldin(gh_w1,(size_t)j,isbf)); }
  } else {
    if(i<2560){ int k=i/10, n=i%10; ghw2t[n*256+k]=f2bf(ldin(gh_w2,(size_t)i,isbf)); }
    else if(i<2560+778){
      int j=i-2560; float v;
      if(j<256)      v=ldin(gh_b1,j,isbf);
      else if(j<512) v=ldin(gh_g,j-256,isbf);
      else if(j<768) v=ldin(gh_bn,j-512,isbf);
      else           v=ldin(gh_b2,j-768,isbf);
      cb[4992+j]=f2bf(v);
    }
  }
}

// ---------------- fused node encoder ----------------
__global__ __launch_bounds__(256) void enc_kernel(
  const void* __restrict__ x, const unsigned short* __restrict__ w1te,
  const unsigned short* __restrict__ w2te, const unsigned short* __restrict__ cb,
  unsigned short* __restrict__ h, const int* __restrict__ flag)
{
  __shared__ __align__(16) unsigned short xs[64][72];
  __shared__ __align__(16) unsigned short t1[64][264];
  int isbf=*flag;
  int m0=blockIdx.x*64;
  int t=threadIdx.x, lane=t&63, w=t>>6, quad=lane>>4, ln=lane&15;
  for(int c2=t;c2<1024;c2+=256){
    int i=c2*4, row=i>>6, col=i&63;
    float v0,v1,v2,v3;
    if(isbf){
      const unsigned short* p=(const unsigned short*)x+(size_t)m0*64+i;
      v0=bf2f(p[0]); v1=bf2f(p[1]); v2=bf2f(p[2]); v3=bf2f(p[3]);
    } else {
      float4 f=*(const float4*)((const float*)x+(size_t)m0*64+i);
      v0=f.x; v1=f.y; v2=f.z; v3=f.w;
    }
    ushort4 o; o.x=f2bf(v0); o.y=f2bf(v1); o.z=f2bf(v2); o.w=f2bf(v3);
    *(ushort4*)&xs[row][col]=o;
  }
  __syncthreads();
  f32x4 a[4][4];
  #pragma unroll
  for(int nt=0;nt<4;nt++){ a[nt][0]={0,0,0,0}; a[nt][1]={0,0,0,0}; a[nt][2]={0,0,0,0}; a[nt][3]={0,0,0,0}; }
  #pragma unroll
  for(int k0i=0;k0i<2;k0i++){
    bf16x8 af[4];
    #pragma unroll
    for(int f=0;f<4;f++) af[f]=*(const bf16x8*)(&xs[f*16+ln][k0i*32+quad*8]);
    #pragma unroll
    for(int nt=0;nt<4;nt++){
      int n=w*64+nt*16+ln;
      bf16x8 bfr=*(const bf16x8*)(w1te+(size_t)n*64+k0i*32+quad*8);
      #pragma unroll
      for(int f=0;f<4;f++) a[nt][f]=__builtin_amdgcn_mfma_f32_16x16x32_bf16(af[f],bfr,a[nt][f],0,0,0);
    }
  }
  #pragma unroll
  for(int nt=0;nt<4;nt++){
    int n=w*64+nt*16+ln;
    float bv=bf2f(cb[3840+n]);
    #pragma unroll
    for(int f=0;f<4;f++)
      #pragma unroll
      for(int r=0;r<4;r++) t1[f*16+quad*4+r][n]=f2bf(a[nt][f][r]+bv);
  }
  __syncthreads();
  {
    int row=t>>2, qq=t&3;
    float s=0.f,s2=0.f;
    for(int c=qq*64;c<qq*64+64;c++){ float v=bf2f(t1[row][c]); s+=v; s2+=v*v; }
    s+=__shfl_xor(s,1); s+=__shfl_xor(s,2);
    s2+=__shfl_xor(s2,1); s2+=__shfl_xor(s2,2);
    float mu=s*(1.f/256.f), var=fmaxf(s2*(1.f/256.f)-mu*mu,0.f);
    float rr=rsqrtf(var+1e-5f);
    for(int c=qq*64;c<qq*64+64;c++){
      float v=bf2f(t1[row][c]);
      t1[row][c]=f2bf(gelu_f((v-mu)*rr*bf2f(cb[4096+c])+bf2f(cb[4352+c])));
    }
  }
  __syncthreads();
  f32x4 b2a[2][4];
  #pragma unroll
  for(int nt=0;nt<2;nt++){ b2a[nt][0]={0,0,0,0}; b2a[nt][1]={0,0,0,0}; b2a[nt][2]={0,0,0,0}; b2a[nt][3]={0,0,0,0}; }
  #pragma unroll
  for(int k0i=0;k0i<8;k0i++){
    bf16x8 af[4];
    #pragma unroll
    for(int f=0;f<4;f++) af[f]=*(const bf16x8*)(&t1[f*16+ln][k0i*32+quad*8]);
    #pragma unroll
    for(int nt=0;nt<2;nt++){
      int n=w*32+nt*16+ln;
      bf16x8 bfr=*(const bf16x8*)(w2te+(size_t)n*256+k0i*32+quad*8);
      #pragma unroll
      for(int f=0;f<4;f++) b2a[nt][f]=__builtin_amdgcn_mfma_f32_16x16x32_bf16(af[f],bfr,b2a[nt][f],0,0,0);
    }
  }
  __syncthreads();
  float* mf=(float*)&t1[0][0];   // [64][132]
  #pragma unroll
  for(int nt=0;nt<2;nt++){
    int n=w*32+nt*16+ln;
    float bv=bf2f(cb[4608+n]);
    #pragma unroll
    for(int f=0;f<4;f++)
      #pragma unroll
      for(int r=0;r<4;r++) mf[(f*16+quad*4+r)*132+n]=b2a[nt][f][r]+bv;
  }
  __syncthreads();
  {
    int row=t>>2, qq=t&3;
    float s=0.f,s2=0.f;
    for(int c=qq*32;c<qq*32+32;c++){ float v=mf[row*132+c]; s+=v; s2+=v*v; }
    s+=__shfl_xor(s,1); s+=__shfl_xor(s,2);
    s2+=__shfl_xor(s2,1); s2+=__shfl_xor(s2,2);
    float mu=s*(1.f/128.f), var=fmaxf(s2*(1.f/128.f)-mu*mu,0.f);
    float rr=rsqrtf(var+1e-5f);
    for(int c=qq*32;c<qq*32+32;c+=2){
      float v0=(mf[row*132+c  ]-mu)*rr*bf2f(cb[4736+c  ])+bf2f(cb[4864+c  ]);
      float v1=(mf[row*132+c+1]-mu)*rr*bf2f(cb[4736+c+1])+bf2f(cb[4864+c+1]);
      *(unsigned int*)(h+(size_t)(m0+row)*128+c)=pack2(v0,v1);
    }
  }
}

// ---------------- UV generation: U = h@W1a + b1, V = h@W1b ----------------
__global__ __launch_bounds__(256) void uvgen_kernel(
  const unsigned short* __restrict__ hrows, const unsigned short* __restrict__ w1t,
  const unsigned short* __restrict__ b1, unsigned short* __restrict__ UV)
{
  __shared__ __align__(16) unsigned short a_t[64][136];
  int t=threadIdx.x;
  int m0=blockIdx.x*64;
  int y=blockIdx.y;
  for(int c=t;c<1024;c+=256){
    int m=c>>4, pp=c&15;
    *(uint4*)&a_t[m][pp*8]=*((const uint4*)(hrows+(size_t)(m0+m)*128)+pp);
  }
  __syncthreads();
  int lane=t&63, w=t>>6, quad=lane>>4, ln=lane&15;
  #pragma unroll
  for(int nt=0;nt<2;nt++){
    int n=w*32+nt*16+ln;
    f32x4 a0={0,0,0,0},a1={0,0,0,0},a2={0,0,0,0},a3={0,0,0,0};
    const unsigned short* wp=w1t+(size_t)n*256+y*128+quad*8;
    #pragma unroll
    for(int k0=0;k0<128;k0+=32){
      bf16x8 bfr=*(const bf16x8*)(wp+k0);
      bf16x8 f0=*(const bf16x8*)(&a_t[ln   ][k0+quad*8]);
      bf16x8 f1=*(const bf16x8*)(&a_t[16+ln][k0+quad*8]);
      bf16x8 f2=*(const bf16x8*)(&a_t[32+ln][k0+quad*8]);
      bf16x8 f3=*(const bf16x8*)(&a_t[48+ln][k0+quad*8]);
      a0=__builtin_amdgcn_mfma_f32_16x16x32_bf16(f0,bfr,a0,0,0,0);
      a1=__builtin_amdgcn_mfma_f32_16x16x32_bf16(f1,bfr,a1,0,0,0);
      a2=__builtin_amdgcn_mfma_f32_16x16x32_bf16(f2,bfr,a2,0,0,0);
      a3=__builtin_amdgcn_mfma_f32_16x16x32_bf16(f3,bfr,a3,0,0,0);
    }
    float bv=y?0.f:bf2f(b1[n]);
    #pragma unroll
    for(int r2=0;r2<4;r2++){
      UV[(size_t)(m0+quad*4+r2   )*256+y*128+n]=f2bf(a0[r2]+bv);
      UV[(size_t)(m0+16+quad*4+r2)*256+y*128+n]=f2bf(a1[r2]+bv);
      UV[(size_t)(m0+32+quad*4+r2)*256+y*128+n]=f2bf(a2[r2]+bv);
      UV[(size_t)(m0+48+quad*4+r2)*256+y*128+n]=f2bf(a3[r2]+bv);
    }
  }
}

// ---------------- fused edge phase: branchless gather + k-split GEMV; XCD-local swizzle ----------------
__global__ __launch_bounds__(128) void edgef_kernel(
  unsigned short* __restrict__ h,
  const unsigned short* __restrict__ UV,      // local rows [gEp*512][256]
  const unsigned short* __restrict__ ss,
  const int* __restrict__ rowptr,
  const unsigned short* __restrict__ w2k,     // [128k][128n]
  const unsigned short* __restrict__ b2,
  const unsigned short* __restrict__ gg, const unsigned short* __restrict__ bbp,
  int b0, int gEp)
{
  __shared__ __align__(16) float aggL[2][4][128];
  __shared__ __align__(16) float po[2][4][128];
  int t=threadIdx.x, lane=t&63, w=t>>6;
  int bid=blockIdx.x;
  int lg=bid%gEp, ch=bid/gEp;     // ch in [0,128): 4-dst chunk
  int g=b0+lg;
  const unsigned short* UVg = UV + (size_t)lg*512*256;
  const unsigned short* ssg = ss + (size_t)g*E_;
  int dbase = ch*4;
  int bnd[5];
  #pragma unroll
  for(int i=0;i<5;i++) bnd[i]=rowptr[g*513+dbase+i];
  // ---- gather: wave w takes its half of each dst's edge range (branchless, masked idx) ----
  #pragma unroll 1
  for(int dd=0;dd<4;dd++){
    int e_lo=bnd[dd], e_hi0=bnd[dd+1];
    int half=(e_hi0-e_lo+1)>>1;
    int es = w ? (e_lo+half) : e_lo;
    int ee = w ? e_hi0       : (e_lo+half);
    unsigned int vdw=*(const unsigned int*)(UVg + (size_t)(dbase+dd)*256 + 128 + lane*2);
    float v0=bf2f((unsigned short)(vdw&0xffffu)), v1=bf2f((unsigned short)(vdw>>16));
    float a0=0.f, a1=0.f;
    int si3,si4,si5;
    unsigned int u0,u1,u2;
    {
      // over-reads (<=6 u16 past range) stay in-ws; idx masked &511
      int s0=__builtin_amdgcn_readfirstlane((int)ssg[es  ])&511;
      int s1=__builtin_amdgcn_readfirstlane((int)ssg[es+1])&511;
      int s2=__builtin_amdgcn_readfirstlane((int)ssg[es+2])&511;
      si3=(int)ssg[es+3]; si4=(int)ssg[es+4]; si5=(int)ssg[es+5];
      u0=*(const unsigned int*)(UVg + (size_t)s0*256 + lane*2);
      u1=*(const unsigned int*)(UVg + (size_t)s1*256 + lane*2);
      u2=*(const unsigned int*)(UVg + (size_t)s2*256 + lane*2);
    }
    #pragma unroll 1
    for(int e=es;e<ee;e++){
      float z0=bf2f((unsigned short)(u0&0xffffu))+v0;
      float z1=bf2f((unsigned short)(u0>>16))+v1;
      u0=u1; u1=u2;
      int s3=__builtin_amdgcn_readfirstlane(si3)&511;
      u2=*(const unsigned int*)(UVg + (size_t)s3*256 + lane*2);
      si3=si4; si4=si5;
      si5=(int)ssg[e+6];
      a0+=gelu_f(z0); a1+=gelu_f(z1);
    }
    aggL[w][dd][lane*2  ]=a0;
    aggL[w][dd][lane*2+1]=a1;
  }
  __syncthreads();
  // ---- GEMV k-split: wave w does all 4 dst over k in [w*64, w*64+64) ----
  float o[4][2];
  #pragma unroll
  for(int dd=0;dd<4;dd++){ o[dd][0]=0.f; o[dd][1]=0.f; }
  #pragma unroll 4
  for(int kk=0;kk<64;kk++){
    int k=w*64+kk;
    unsigned int wdw=*(const unsigned int*)(w2k+(size_t)k*128+lane*2);
    float w0=bf2f((unsigned short)(wdw&0xffffu));
    float w1=bf2f((unsigned short)(wdw>>16));
    #pragma unroll
    for(int dd=0;dd<4;dd++){
      float av=aggL[0][dd][k]+aggL[1][dd][k];
      o[dd][0]+=av*w0; o[dd][1]+=av*w1;
    }
  }
  #pragma unroll
  for(int dd=0;dd<4;dd++){
    po[w][dd][lane*2  ]=o[dd][0];
    po[w][dd][lane*2+1]=o[dd][1];
  }
  __syncthreads();
  // ---- combine partials + deg*b2 + residual + LN: wave w owns dst pair {2w, 2w+1} ----
  #pragma unroll 1
  for(int p=0;p<2;p++){
    int di=w*2+p;
    int d = dbase + di;
    float deg=(float)(bnd[di+1]-bnd[di]);
    float o0=bf2f(b2[lane*2  ])*deg + po[0][di][lane*2  ] + po[1][di][lane*2  ];
    float o1=bf2f(b2[lane*2+1])*deg + po[0][di][lane*2+1] + po[1][di][lane*2+1];
    size_t base=(size_t)(g*512+d)*128;
    unsigned int hdw=*(const unsigned int*)(h+base+lane*2);
    float x0=bf2f((unsigned short)(hdw&0xffffu))+o0;
    float x1=bf2f((unsigned short)(hdw>>16))+o1;
    float s1=x0+x1, s2=x0*x0+x1*x1;
    #pragma unroll
    for(int off=32;off>0;off>>=1){ s1+=__shfl_xor(s1,off); s2+=__shfl_xor(s2,off); }
    float mu=s1*(1.f/128.f), var=fmaxf(s2*(1.f/128.f)-mu*mu,0.f);
    float rr=rsqrtf(var+1e-5f);
    float y0=(x0-mu)*rr*bf2f(gg[lane*2  ])+bf2f(bbp[lane*2  ]);
    float y1=(x1-mu)*rr*bf2f(gg[lane*2+1])+bf2f(bbp[lane*2+1]);
    *(unsigned int*)(h+base+lane*2)=pack2(y0,y1);
  }
}

// ---------------- fused QKV + flash attention: per (graph, head, q-QUARTER), XCD-local swizzle ----------------
__global__ __launch_bounds__(256) void attnf_kernel(
  const unsigned short* __restrict__ h, const unsigned short* __restrict__ wqkv,
  const unsigned short* __restrict__ bq, unsigned short* __restrict__ obuf, int b0, int gA)
{
  __shared__ __align__(16) unsigned short Qs[128][40];
  __shared__ __align__(16) unsigned short Ks[64][72];
  __shared__ __align__(16) unsigned short Vts[32][72];
  __shared__ __align__(16) unsigned short Ps[64][72];
  int bx=blockIdx.x;
  int lg=bx%gA; int rr2=bx/gA; int hh=rr2&3, qq4=rr2>>2;
  int g=b0+lg;
  int t=threadIdx.x, lane=t&63, w=t>>6, quad=lane>>4, ln=lane&15;
  const unsigned short* hg=h+(size_t)g*512*128;
  const float sc=0.17677669529663689f;
  bf16x8 wk[2][4], wv[2][4];
  #pragma unroll
  for(int nt=0;nt<2;nt++)
    #pragma unroll
    for(int k0i=0;k0i<4;k0i++){
      int n=hh*32+nt*16+ln;
      wk[nt][k0i]=*(const bf16x8*)(wqkv+(size_t)(128+n)*128+k0i*32+quad*8);
      wv[nt][k0i]=*(const bf16x8*)(wqkv+(size_t)(256+n)*128+k0i*32+quad*8);
    }
  #pragma unroll
  for(int qt=0;qt<2;qt++){
    int r0=qq4*128+qt*64+w*16;
    bf16x8 af[4];
    #pragma unroll
    for(int k0i=0;k0i<4;k0i++) af[k0i]=*(const bf16x8*)(hg+(size_t)(r0+ln)*128+k0i*32+quad*8);
    #pragma unroll
    for(int nt=0;nt<2;nt++){
      int dim=nt*16+ln;
      f32x4 c={0,0,0,0};
      #pragma unroll
      for(int k0i=0;k0i<4;k0i++){
        bf16x8 bfr=*(const bf16x8*)(wqkv+(size_t)(hh*32+dim)*128+k0i*32+quad*8);
        c=__builtin_amdgcn_mfma_f32_16x16x32_bf16(af[k0i],bfr,c,0,0,0);
      }
      float bv=bf2f(bq[hh*32+dim]);
      #pragma unroll
      for(int r=0;r<4;r++) Qs[qt*64+w*16+quad*4+r][dim]=f2bf((c[r]+bv)*sc);
    }
  }
  f32x4 O[2][2]; float Lp[2][4];
  #pragma unroll
  for(int qt=0;qt<2;qt++){ O[qt][0]={0,0,0,0}; O[qt][1]={0,0,0,0};
    #pragma unroll
    for(int r=0;r<4;r++) Lp[qt][r]=0.f; }
  for(int kc=0;kc<8;kc++){
    __syncthreads();
    {
      int r0=kc*64+w*16;
      bf16x8 af[4];
      #pragma unroll
      for(int k0i=0;k0i<4;k0i++) af[k0i]=*(const bf16x8*)(hg+(size_t)(r0+ln)*128+k0i*32+quad*8);
      #pragma unroll
      for(int nt=0;nt<2;nt++){
        int dim=nt*16+ln;
        f32x4 ck={0,0,0,0}, cv={0,0,0,0};
        #pragma unroll
        for(int k0i=0;k0i<4;k0i++){
          ck=__builtin_amdgcn_mfma_f32_16x16x32_bf16(af[k0i],wk[nt][k0i],ck,0,0,0);
          cv=__builtin_amdgcn_mfma_f32_16x16x32_bf16(af[k0i],wv[nt][k0i],cv,0,0,0);
        }
        float bk=bf2f(bq[128+hh*32+dim]), bv2=bf2f(bq[256+hh*32+dim]);
        #pragma unroll
        for(int r=0;r<4;r++){
          int key=w*16+quad*4+r;
          Ks[key][dim]=f2bf(ck[r]+bk);
          Vts[dim][key]=f2bf(cv[r]+bv2);
        }
      }
    }
    __syncthreads();
    #pragma unroll
    for(int qt=0;qt<2;qt++){
      bf16x8 qf=*(const bf16x8*)(&Qs[qt*64+w*16+ln][quad*8]);
      f32x4 s[4];
      #pragma unroll
      for(int f=0;f<4;f++){
        bf16x8 kf=*(const bf16x8*)(&Ks[f*16+ln][quad*8]);
        f32x4 z={0,0,0,0};
        s[f]=__builtin_amdgcn_mfma_f32_16x16x32_bf16(qf,kf,z,0,0,0);
      }
      #pragma unroll
      for(int f=0;f<4;f++)
        #pragma unroll
        for(int r=0;r<4;r++){
          float pe=__expf(fminf(s[f][r],30.0f));
          Ps[w*16+quad*4+r][f*16+ln]=f2bf(pe);
          Lp[qt][r]+=pe;
        }
      #pragma unroll
      for(int s2=0;s2<2;s2++){
        bf16x8 pf=*(const bf16x8*)(&Ps[w*16+ln][s2*32+quad*8]);
        bf16x8 v0=*(const bf16x8*)(&Vts[ln   ][s2*32+quad*8]);
        bf16x8 v1=*(const bf16x8*)(&Vts[16+ln][s2*32+quad*8]);
        O[qt][0]=__builtin_amdgcn_mfma_f32_16x16x32_bf16(pf,v0,O[qt][0],0,0,0);
        O[qt][1]=__builtin_amdgcn_mfma_f32_16x16x32_bf16(pf,v1,O[qt][1],0,0,0);
      }
    }
  }
  #pragma unroll
  for(int qt=0;qt<2;qt++){
    #pragma unroll
    for(int o=1;o<16;o<<=1)
      #pragma unroll
      for(int r=0;r<4;r++) Lp[qt][r]+=__shfl_xor(Lp[qt][r],o);
    #pragma unroll
    for(int r=0;r<4;r++){
      float inv=1.0f/Lp[qt][r];
      size_t row=(size_t)lg*512+qq4*128+qt*64+w*16+quad*4+r;
      obuf[row*128+hh*32+ln   ]=f2bf(O[qt][0][r]*inv);
      obuf[row*128+hh*32+16+ln]=f2bf(O[qt][1][r]*inv);
    }
  }
}

// ---------------- oproj + residual + LN ----------------
__global__ __launch_bounds__(256) void oproj_kernel(
  const unsigned short* __restrict__ obuf, const unsigned short* __restrict__ wo,
  const unsigned short* __restrict__ bo, unsigned short* __restrict__ h,
  const unsigned short* __restrict__ gg, const unsigned short* __restrict__ bbp, int b0)
{
  __shared__ __align__(16) unsigned short a_t[64][136];
  __shared__ float mf[64][132];
  int t=threadIdx.x, lane=t&63, w=t>>6, quad=lane>>4, ln=lane&15;
  int m0=blockIdx.x*64;
  for(int c=t;c<64*16;c+=256){
    int m=c>>4, pp=c&15;
    *(uint4*)&a_t[m][pp*8]=*((const uint4*)(obuf+(size_t)(m0+m)*128)+pp);
  }
  __syncthreads();
  #pragma unroll
  for(int nt=0;nt<2;nt++){
    int n=w*32+nt*16+ln;
    f32x4 a0={0,0,0,0},a1={0,0,0,0},a2={0,0,0,0},a3={0,0,0,0};
    const unsigned short* wp=wo+(size_t)n*128+quad*8;
    #pragma unroll
    for(int k0=0;k0<128;k0+=32){
      bf16x8 bfr=*(const bf16x8*)(wp+k0);
      bf16x8 f0=*(const bf16x8*)(&a_t[ln   ][k0+quad*8]);
      bf16x8 f1=*(const bf16x8*)(&a_t[16+ln][k0+quad*8]);
      bf16x8 f2=*(const bf16x8*)(&a_t[32+ln][k0+quad*8]);
      bf16x8 f3=*(const bf16x8*)(&a_t[48+ln][k0+quad*8]);
      a0=__builtin_amdgcn_mfma_f32_16x16x32_bf16(f0,bfr,a0,0,0,0);
      a1=__builtin_amdgcn_mfma_f32_16x16x32_bf16(f1,bfr,a1,0,0,0);
      a2=__builtin_amdgcn_mfma_f32_16x16x32_bf16(f2,bfr,a2,0,0,0);
      a3=__builtin_amdgcn_mfma_f32_16x16x32_bf16(f3,bfr,a3,0,0,0);
    }
    float bv=bf2f(bo[n]);
    #pragma unroll
    for(int r=0;r<4;r++){
      mf[quad*4+r   ][n]=a0[r]+bv;
      mf[16+quad*4+r][n]=a1[r]+bv;
      mf[32+quad*4+r][n]=a2[r]+bv;
      mf[48+quad*4+r][n]=a3[r]+bv;
    }
  }
  __syncthreads();
  {
    int row=t>>2, qq=t&3;
    size_t base=(size_t)(b0*512+m0+row)*128;
    float s=0.f,s2=0.f;
    float vals[32];
    for(int j=0;j<32;j++){
      int c=qq*32+j;
      float v=bf2f(h[base+c])+mf[row][c];
      vals[j]=v; s+=v; s2+=v*v;
    }
    s+=__shfl_xor(s,1); s+=__shfl_xor(s,2);
    s2+=__shfl_xor(s2,1); s2+=__shfl_xor(s2,2);
    float mu=s*(1.f/128.f), var=fmaxf(s2*(1.f/128.f)-mu*mu,0.f);
    float rr=rsqrtf(var+1e-5f);
    for(int j=0;j<32;j+=2){
      int c=qq*32+j;
      float v0=(vals[j]  -mu)*rr*bf2f(gg[c  ])+bf2f(bbp[c  ]);
      float v1=(vals[j+1]-mu)*rr*bf2f(gg[c+1])+bf2f(bbp[c+1]);
      *(unsigned int*)(h+base+c)=pack2(v0,v1);
    }
  }
}

// ---------------- pooling partials ----------------
__global__ __launch_bounds__(256) void poolp_kernel(
  const unsigned short* __restrict__ h, float* __restrict__ part)
{
  __shared__ float ps[256], ps2[256], pm[256];
  int b=blockIdx.x, c=blockIdx.y;
  int t=threadIdx.x, d=t&127, hf=t>>7;
  float s=0.f,s2=0.f,mx=-1e30f;
  for(int r=hf*32;r<hf*32+32;r++){
    float v=bf2f(h[((size_t)(b*512+c*64+r))*128+d]);
    s+=v; s2+=v*v; mx=fmaxf(mx,v);
  }
  ps[t]=s; ps2[t]=s2; pm[t]=mx;
  __syncthreads();
  if(t<128){
    s=ps[t]+ps[128+t]; s2=ps2[t]+ps2[128+t]; mx=fmaxf(pm[t],pm[128+t]);
    size_t base=((size_t)(b*8+c))*384;
    part[base+t]=s; part[base+128+t]=s2; part[base+256+t]=mx;
  }
}

// ---------------- graph head: finalize pooling + MLP ----------------
__global__ __launch_bounds__(256) void head_kernel(
  const float* __restrict__ part, const unsigned short* __restrict__ ghw1t,
  const unsigned short* __restrict__ ghw2t, const unsigned short* __restrict__ cb,
  void* __restrict__ out, const int* __restrict__ flag)
{
  int isbf=*flag;
  int b=blockIdx.x, t=threadIdx.x;
  __shared__ float pl[512];
  __shared__ float gl[256];
  __shared__ float red[16];
  if(t<128){
    float s=0.f,s2=0.f,mx=-1e30f;
    for(int c=0;c<8;c++){
      size_t base=((size_t)(b*8+c))*384;
      s += part[base+t];
      s2+= part[base+128+t];
      mx = fmaxf(mx, part[base+256+t]);
    }
    float mean=s*(1.f/512.f);
    float var=fmaxf(s2*(1.f/512.f)-mean*mean,0.f);
    float sd=sqrtf(var+1e-6f);
    pl[t]=mean; pl[128+t]=s; pl[256+t]=mx; pl[384+t]=sd;
  }
  __syncthreads();
  float a=bf2f(cb[4992+t]);
  const unsigned short* wr=ghw1t+(size_t)t*512;
  for(int k0=0;k0<512;k0+=8){
    bf16x8 wv=*(const bf16x8*)(wr+k0);
    const unsigned short* wp=(const unsigned short*)&wv;
    #pragma unroll
    for(int j=0;j<8;j++) a+=pl[k0+j]*bf2f(wp[j]);
  }
  float u=gelu_f(a);
  float S,S2; block_sum2(u,u*u,S,S2,red,4);
  float mu=S*(1.f/256.f), var=fmaxf(S2*(1.f/256.f)-mu*mu,0.f);
  float r=rsqrtf(var+1e-5f);
  gl[t]=(u-mu)*r*bf2f(cb[5248+t])+bf2f(cb[5504+t]);
  __syncthreads();
  if(t<10){
    float o=bf2f(cb[5760+t]);
    const unsigned short* wr2=ghw2t+(size_t)t*256;
    for(int k0=0;k0<256;k0+=8){
      bf16x8 wv=*(const bf16x8*)(wr2+k0);
      const unsigned short* wp=(const unsigned short*)&wv;
      #pragma unroll
      for(int j=0;j<8;j++) o+=gl[k0+j]*bf2f(wp[j]);
    }
    if(isbf) ((unsigned short*)out)[b*10+t]=f2bf(o);
    else     ((float*)out)[b*10+t]=o;
  }
}

extern "C" void kernel_launch(void* const* d_in, const int* in_sizes, int n_in,
                              void* d_out, int out_size, void* d_ws, size_t ws_size,
                              hipStream_t stream)
{
  const void* x      =d_in[0];
  const int*  src    =(const int*)d_in[1];
  const int*  dstp   =(const int*)d_in[2];
  const void* enc_w1 =d_in[3];  const void* enc_b1 =d_in[4];
  const void* enc_g1 =d_in[5];  const void* enc_bn1=d_in[6];
  const void* enc_w2 =d_in[7];  const void* enc_b2 =d_in[8];
  const void* enc_g2 =d_in[9];  const void* enc_bn2=d_in[10];
  const void* msg_w1 =d_in[11]; const void* msg_b1 =d_in[12];
  const void* msg_w2 =d_in[13]; const void* msg_b2 =d_in[14];
  const void* msg_g  =d_in[15]; const void* msg_bb =d_in[16];
  const void* qw     =d_in[17]; const void* qb     =d_in[18];
  const void* kw     =d_in[19]; const void* kb     =d_in[20];
  const void* vw     =d_in[21]; const void* vb     =d_in[22];
  const void* ow     =d_in[23]; const void* ob     =d_in[24];
  const void* attn_g =d_in[25]; const void* attn_b =d_in[26];
  const void* gh_w1  =d_in[27]; const void* gh_b1  =d_in[28];
  const void* gh_g   =d_in[29]; const void* gh_bn  =d_in[30];
  const void* gh_w2  =d_in[31]; const void* gh_b2  =d_in[32];
  (void)in_sizes; (void)n_in; (void)out_size;

  const size_t MB=1024*1024;
  char* base=(char*)d_ws;
  unsigned short* h    =(unsigned short*)(base);                 // 4 MB
  unsigned short* w1t  =(unsigned short*)(base + 4194304);
  unsigned short* w2k  =(unsigned short*)(base + 4390912);
  unsigned short* qkvt =(unsigned short*)(base + 4489216);
  unsigned short* owt  =(unsigned short*)(base + 4784128);
  unsigned short* w1te =(unsigned short*)(base + 4882432);
  unsigned short* w2te =(unsigned short*)(base + 4915200);
  unsigned short* ghw1t=(unsigned short*)(base + 4980736);
  unsigned short* ghw2t=(unsigned short*)(base + 5242880);
  unsigned short* cb   =(unsigned short*)(base + 5248000);
  int*   rowptr        =(int*)(base + 5325312);                  // 65664 B
  int*   flag          =(int*)(base + 5390976);
  int*   cnt           =(int*)(base + 5391360);                  // 65536 B sort counters
  unsigned short* ssrt =(unsigned short*)(base + 5505024);       // 512 KB (+edgef over-reads land in R)
  char* R              = base + 6029312;                          // shared region

  int epass, apass;
  if(ws_size >= (size_t)(14.5*MB)){ epass=1; apass=1; }
  else if(ws_size >= 10*MB){ epass=2; apass=1; }
  else { epass=4; apass=2; }
  int gEp=B_/epass, gA=B_/apass;
  int rowsA=gA*512;
  float* part=(float*)R;   // pool partials: 32*8*384*4 = 393 KB (R free after layer loop)

  sniff_kernel<<<1,64,0,stream>>>((const unsigned int*)x, flag);
  hipMemsetAsync(cnt,0,65536,stream);
  count_kernel<<<dim3(B_,8),256,0,stream>>>(dstp,cnt);
  scan_kernel<<<B_,256,0,stream>>>(cnt,rowptr);
  scatter_kernel<<<dim3(B_,8),256,0,stream>>>(src,dstp,cnt,ssrt);
  prep_kernel<<<dim3(128,27),256,0,stream>>>(msg_w1,msg_w2,qw,kw,vw,ow,qb,kb,vb,
      ob,msg_b1,msg_b2,msg_g,msg_bb,attn_g,attn_b,
      enc_w1,enc_w2,enc_b1,enc_g1,enc_bn1,enc_b2,enc_g2,enc_bn2,
      gh_w1,gh_w2,gh_b1,gh_g,gh_bn,gh_b2,
      w1t,w2k,qkvt,owt,w1te,w2te,ghw1t,ghw2t,cb,flag);

  enc_kernel<<<BN_/64,256,0,stream>>>(x,w1te,w2te,cb,h,flag);

  for(int l=0;l<3;l++){
    for(int ep=0;ep<epass;ep++){
      int b0=ep*gEp;
      unsigned short* UV=(unsigned short*)R;   // gEp*512 x 256 bf16
      uvgen_kernel<<<dim3(gEp*8,2),256,0,stream>>>(h+(size_t)b0*512*128,
          w1t+(size_t)l*32768, cb+1536+l*128, UV);
      edgef_kernel<<<gEp*128,128,0,stream>>>(h,UV,ssrt,rowptr,
          w2k+(size_t)l*16384, cb+1920+l*128, cb+2304+l*128, cb+2688+l*128, b0, gEp);
    }
    for(int ap=0;ap<apass;ap++){
      int b0=ap*gA;
      unsigned short* obuf=(unsigned short*)R;
      attnf_kernel<<<gA*16,256,0,stream>>>(h, qkvt+(size_t)l*49152, cb+l*384, obuf, b0, gA);
      oproj_kernel<<<rowsA/64,256,0,stream>>>(obuf, owt+(size_t)l*16384,
          cb+1152+l*128, h, cb+3072+l*128, cb+3456+l*128, b0);
    }
  }
  poolp_kernel<<<dim3(B_,8),256,0,stream>>>(h,part);
  head_kernel<<<B_,256,0,stream>>>(part,ghw1t,ghw2t,cb,d_out,flag);
}

// Round 16
// 435.445 us; speedup vs baseline: 1.1060x; 1.0472x over previous
//
#include <hip/hip_runtime.h>
#include <cmath>

#define B_   32
#define N_   512
#define E_   8192
#define BN_  16384
#define D_   128

typedef short bf16x8 __attribute__((ext_vector_type(8)));
typedef float f32x4  __attribute__((ext_vector_type(4)));

static __device__ __forceinline__ float bf2f(unsigned short u){
  union{unsigned int i; float f;} v; v.i = ((unsigned int)u)<<16; return v.f;
}
static __device__ __forceinline__ unsigned short f2bf(float f){
  union{unsigned int i; float f;} v; v.f=f;
  unsigned int x=v.i;
  return (unsigned short)((x + 0x7fffu + ((x>>16)&1u))>>16);
}
static __device__ __forceinline__ unsigned int pack2(float a, float b){
  return (unsigned int)f2bf(a) | ((unsigned int)f2bf(b)<<16);
}
// precise GELU (A&S erf, |err|<=1.5e-7) - cold paths
static __device__ __forceinline__ float gelu_f(float x){
  float xs=x*0.70710678118654752f;
  float ax=fabsf(xs);
  float t=__builtin_amdgcn_rcpf(1.0f+0.3275911f*ax);
  float p=t*(0.254829592f+t*(-0.284496736f+t*(1.421413741f+t*(-1.453152027f+t*1.061405429f))));
  float er=1.0f - p*__expf(-ax*ax);
  er = (xs<0.f)? -er : er;
  return 0.5f*x*(1.0f+er);
}
// tanh-form GELU: x/(1+e^{x(c1+c2 x^2)}), |dev from erf-gelu|<=3e-4 (<< bf16 noise) - hot path
static __device__ __forceinline__ float gelu_t(float x){
  float x2=x*x;
  float y=x*(-1.5957691216f + x2*(-0.0713548162f));
  float e=__expf(y);
  return x*__builtin_amdgcn_rcpf(1.0f+e);
}
static __device__ __forceinline__ float ldin(const void* p, size_t i, int isbf){
  return isbf ? bf2f(((const unsigned short*)p)[i]) : ((const float*)p)[i];
}

static __device__ __forceinline__ void block_sum2(float a, float b, float&A, float&Bv, float* red, int nw){
  int lane=threadIdx.x&63, w=threadIdx.x>>6;
  #pragma unroll
  for(int o=32;o>0;o>>=1){ a+=__shfl_down(a,o); b+=__shfl_down(b,o); }
  if(lane==0){ red[w]=a; red[8+w]=b; }
  __syncthreads();
  float sa=0.f, sb=0.f;
  for(int i=0;i<nw;i++){ sa+=red[i]; sb+=red[8+i]; }
  __syncthreads();
  A=sa; Bv=sb;
}

// ---------------- dtype sniff ----------------
__global__ void sniff_kernel(const unsigned int* __restrict__ xw, int* __restrict__ flag){
  int t=threadIdx.x;
  int cnt=0;
  for(int i=0;i<32;i++){
    unsigned int w=xw[t+64*i];
    float v=bf2f((unsigned short)(w&0xffffu));
    float av=fabsf(v);
    if(v==0.0f || (av>=6e-5f && av<=8.0f)) cnt++;
  }
  #pragma unroll
  for(int o=32;o>0;o>>=1) cnt+=__shfl_down(cnt,o);
  if(t==0) *flag=(cnt>=1024)?1:0;
}

// ---------------- parallel 3-stage counting sort by dst ----------------
__global__ __launch_bounds__(256) void count_kernel(
  const int* __restrict__ dst, int* __restrict__ cnt)
{
  __shared__ int lc[512];
  int g=blockIdx.x, c=blockIdx.y, t=threadIdx.x;
  for(int i=t;i<512;i+=256) lc[i]=0;
  __syncthreads();
  for(int e=t;e<1024;e+=256) atomicAdd(&lc[dst[(size_t)g*E_+c*1024+e]],1);
  __syncthreads();
  for(int i=t;i<512;i+=256){ int v=lc[i]; if(v) atomicAdd(&cnt[g*512+i],v); }
}

__global__ __launch_bounds__(256) void scan_kernel(
  int* __restrict__ cnt, int* __restrict__ rowptr)
{
  __shared__ int sc[512];
  int g=blockIdx.x, t=threadIdx.x;
  for(int i=t;i<512;i+=256) sc[i]=cnt[g*512+i];
  __syncthreads();
  if(t==0){
    int acc=0;
    for(int i=0;i<512;i++){ int c=sc[i]; rowptr[g*513+i]=acc; cnt[g*512+i]=acc; acc+=c; }
    rowptr[g*513+512]=acc;
  }
}

__global__ __launch_bounds__(256) void scatter_kernel(
  const int* __restrict__ src, const int* __restrict__ dst,
  int* __restrict__ off, unsigned short* __restrict__ ss)
{
  int g=blockIdx.x, c=blockIdx.y, t=threadIdx.x;
  for(int e=t;e<1024;e+=256){
    size_t idx=(size_t)g*E_+c*1024+e;
    int d=dst[idx];
    int pos=atomicAdd(&off[g*512+d],1);
    ss[(size_t)g*E_+pos]=(unsigned short)src[idx];
  }
}

// cb layout (bf16 canonical):
// [0,1152) qkv bias | [1152,1536) ob | [1536,1920) msg_b1 | [1920,2304) msg_b2
// [2304,2688) msg_g | [2688,3072) msg_bb | [3072,3456) attn_g | [3456,3840) attn_b
// [3840,4096) enc_b1 | [4096,4352) enc_g1 | [4352,4608) enc_bn1
// [4608,4736) enc_b2 | [4736,4864) enc_g2 | [4864,4992) enc_bn2
// [4992,5248) gh_b1 | [5248,5504) gh_g | [5504,5760) gh_bn | [5760,5776) gh_b2
__global__ __launch_bounds__(256) void prep_kernel(
  const void* __restrict__ msg_w1, const void* __restrict__ msg_w2,
  const void* __restrict__ qw, const void* __restrict__ kw,
  const void* __restrict__ vw, const void* __restrict__ ow,
  const void* __restrict__ qb, const void* __restrict__ kb, const void* __restrict__ vb,
  const void* __restrict__ ob, const void* __restrict__ msg_b1, const void* __restrict__ msg_b2,
  const void* __restrict__ msg_g, const void* __restrict__ msg_bb,
  const void* __restrict__ attn_g, const void* __restrict__ attn_b,
  const void* __restrict__ enc_w1, const void* __restrict__ enc_w2,
  const void* __restrict__ enc_b1, const void* __restrict__ enc_g1, const void* __restrict__ enc_bn1,
  const void* __restrict__ enc_b2, const void* __restrict__ enc_g2, const void* __restrict__ enc_bn2,
  const void* __restrict__ gh_w1, const void* __restrict__ gh_w2,
  const void* __restrict__ gh_b1, const void* __restrict__ gh_g,
  const void* __restrict__ gh_bn, const void* __restrict__ gh_b2,
  unsigned short* __restrict__ w1t, unsigned short* __restrict__ w2k,
  unsigned short* __restrict__ qkvt, unsigned short* __restrict__ owt,
  unsigned short* __restrict__ w1te, unsigned short* __restrict__ w2te,
  unsigned short* __restrict__ ghw1t, unsigned short* __restrict__ ghw2t,
  unsigned short* __restrict__ cb, const int* __restrict__ flag)
{
  int isbf=*flag;
  int job=blockIdx.y;
  int i=blockIdx.x*256+threadIdx.x;
  if(job<3){ // msg_w1[l] [256][128] -> [128][256] n-major
    if(i<32768){ int l=job; int k=i>>7, n=i&127; w1t[l*32768 + n*256 + k]=f2bf(ldin(msg_w1,(size_t)l*32768+i,isbf)); }
  } else if(job<6){ // msg_w2[l] straight copy [128k][128n]
    int l=job-3; if(i<16384){ w2k[l*16384 + i]=f2bf(ldin(msg_w2,(size_t)l*16384+i,isbf)); }
  } else if(job<15){
    int r=job-6, l=r/3, which=r%3;
    if(i<16384){ int k=i>>7, n=i&127;
      const void* w=(which==0)?qw:((which==1)?kw:vw);
      qkvt[l*49152 + (which*128+n)*128 + k]=f2bf(ldin(w,(size_t)l*16384+i,isbf)); }
  } else if(job<18){
    int l=job-15; if(i<16384){ int k=i>>7, n=i&127; owt[l*16384 + n*128 + k]=f2bf(ldin(ow,(size_t)l*16384+i,isbf)); }
  } else if(job==18){
    if(i<3840){
      float v;
      if(i<1152){ int l=i/384, j=i%384, which=j>>7, jj=j&127;
        const void* bb=(which==0)?qb:((which==1)?kb:vb);
        v=ldin(bb,(size_t)l*128+jj,isbf);
      } else {
        int i2=i-1152; int r=i2/384; int rem=i2%384;
        const void* s = (r==0)?ob:((r==1)?msg_b1:((r==2)?msg_b2:((r==3)?msg_g:((r==4)?msg_bb:((r==5)?attn_g:attn_b)))));
        v=ldin(s,(size_t)rem,isbf);
      }
      cb[i]=f2bf(v);
    }
  } else if(job==19){
    if(i<1152){
      float v;
      if(i<256)       v=ldin(enc_b1,i,isbf);
      else if(i<512)  v=ldin(enc_g1,i-256,isbf);
      else if(i<768)  v=ldin(enc_bn1,i-512,isbf);
      else if(i<896)  v=ldin(enc_b2,i-768,isbf);
      else if(i<1024) v=ldin(enc_g2,i-896,isbf);
      else            v=ldin(enc_bn2,i-1024,isbf);
      cb[3840+i]=f2bf(v);
    }
  } else if(job==20){
    if(i<16384){ int k=i>>8, n=i&255; w1te[n*64+k]=f2bf(ldin(enc_w1,(size_t)i,isbf)); }
  } else if(job==21){
    if(i<32768){ int k=i>>7, n=i&127; w2te[n*256+k]=f2bf(ldin(enc_w2,(size_t)i,isbf)); }
  } else if(job<26){
    int p=job-22; int j=p*32768+i;
    if(i<32768){ int k=j>>8, n=j&255; ghw1t[n*512+k]=f2bf(ldin(gh_w1,(size_t)j,isbf)); }
  } else {
    if(i<2560){ int k=i/10, n=i%10; ghw2t[n*256+k]=f2bf(ldin(gh_w2,(size_t)i,isbf)); }
    else if(i<2560+778){
      int j=i-2560; float v;
      if(j<256)      v=ldin(gh_b1,j,isbf);
      else if(j<512) v=ldin(gh_g,j-256,isbf);
      else if(j<768) v=ldin(gh_bn,j-512,isbf);
      else           v=ldin(gh_b2,j-768,isbf);
      cb[4992+j]=f2bf(v);
    }
  }
}

// ---------------- fused node encoder ----------------
__global__ __launch_bounds__(256) void enc_kernel(
  const void* __restrict__ x, const unsigned short* __restrict__ w1te,
  const unsigned short* __restrict__ w2te, const unsigned short* __restrict__ cb,
  unsigned short* __restrict__ h, const int* __restrict__ flag)
{
  __shared__ __align__(16) unsigned short xs[64][72];
  __shared__ __align__(16) unsigned short t1[64][264];
  int isbf=*flag;
  int m0=blockIdx.x*64;
  int t=threadIdx.x, lane=t&63, w=t>>6, quad=lane>>4, ln=lane&15;
  for(int c2=t;c2<1024;c2+=256){
    int i=c2*4, row=i>>6, col=i&63;
    float v0,v1,v2,v3;
    if(isbf){
      const unsigned short* p=(const unsigned short*)x+(size_t)m0*64+i;
      v0=bf2f(p[0]); v1=bf2f(p[1]); v2=bf2f(p[2]); v3=bf2f(p[3]);
    } else {
      float4 f=*(const float4*)((const float*)x+(size_t)m0*64+i);
      v0=f.x; v1=f.y; v2=f.z; v3=f.w;
    }
    ushort4 o; o.x=f2bf(v0); o.y=f2bf(v1); o.z=f2bf(v2); o.w=f2bf(v3);
    *(ushort4*)&xs[row][col]=o;
  }
  __syncthreads();
  f32x4 a[4][4];
  #pragma unroll
  for(int nt=0;nt<4;nt++){ a[nt][0]={0,0,0,0}; a[nt][1]={0,0,0,0}; a[nt][2]={0,0,0,0}; a[nt][3]={0,0,0,0}; }
  #pragma unroll
  for(int k0i=0;k0i<2;k0i++){
    bf16x8 af[4];
    #pragma unroll
    for(int f=0;f<4;f++) af[f]=*(const bf16x8*)(&xs[f*16+ln][k0i*32+quad*8]);
    #pragma unroll
    for(int nt=0;nt<4;nt++){
      int n=w*64+nt*16+ln;
      bf16x8 bfr=*(const bf16x8*)(w1te+(size_t)n*64+k0i*32+quad*8);
      #pragma unroll
      for(int f=0;f<4;f++) a[nt][f]=__builtin_amdgcn_mfma_f32_16x16x32_bf16(af[f],bfr,a[nt][f],0,0,0);
    }
  }
  #pragma unroll
  for(int nt=0;nt<4;nt++){
    int n=w*64+nt*16+ln;
    float bv=bf2f(cb[3840+n]);
    #pragma unroll
    for(int f=0;f<4;f++)
      #pragma unroll
      for(int r=0;r<4;r++) t1[f*16+quad*4+r][n]=f2bf(a[nt][f][r]+bv);
  }
  __syncthreads();
  {
    int row=t>>2, qq=t&3;
    float s=0.f,s2=0.f;
    for(int c=qq*64;c<qq*64+64;c++){ float v=bf2f(t1[row][c]); s+=v; s2+=v*v; }
    s+=__shfl_xor(s,1); s+=__shfl_xor(s,2);
    s2+=__shfl_xor(s2,1); s2+=__shfl_xor(s2,2);
    float mu=s*(1.f/256.f), var=fmaxf(s2*(1.f/256.f)-mu*mu,0.f);
    float rr=rsqrtf(var+1e-5f);
    for(int c=qq*64;c<qq*64+64;c++){
      float v=bf2f(t1[row][c]);
      t1[row][c]=f2bf(gelu_f((v-mu)*rr*bf2f(cb[4096+c])+bf2f(cb[4352+c])));
    }
  }
  __syncthreads();
  f32x4 b2a[2][4];
  #pragma unroll
  for(int nt=0;nt<2;nt++){ b2a[nt][0]={0,0,0,0}; b2a[nt][1]={0,0,0,0}; b2a[nt][2]={0,0,0,0}; b2a[nt][3]={0,0,0,0}; }
  #pragma unroll
  for(int k0i=0;k0i<8;k0i++){
    bf16x8 af[4];
    #pragma unroll
    for(int f=0;f<4;f++) af[f]=*(const bf16x8*)(&t1[f*16+ln][k0i*32+quad*8]);
    #pragma unroll
    for(int nt=0;nt<2;nt++){
      int n=w*32+nt*16+ln;
      bf16x8 bfr=*(const bf16x8*)(w2te+(size_t)n*256+k0i*32+quad*8);
      #pragma unroll
      for(int f=0;f<4;f++) b2a[nt][f]=__builtin_amdgcn_mfma_f32_16x16x32_bf16(af[f],bfr,b2a[nt][f],0,0,0);
    }
  }
  __syncthreads();
  float* mf=(float*)&t1[0][0];   // [64][132]
  #pragma unroll
  for(int nt=0;nt<2;nt++){
    int n=w*32+nt*16+ln;
    float bv=bf2f(cb[4608+n]);
    #pragma unroll
    for(int f=0;f<4;f++)
      #pragma unroll
      for(int r=0;r<4;r++) mf[(f*16+quad*4+r)*132+n]=b2a[nt][f][r]+bv;
  }
  __syncthreads();
  {
    int row=t>>2, qq=t&3;
    float s=0.f,s2=0.f;
    for(int c=qq*32;c<qq*32+32;c++){ float v=mf[row*132+c]; s+=v; s2+=v*v; }
    s+=__shfl_xor(s,1); s+=__shfl_xor(s,2);
    s2+=__shfl_xor(s2,1); s2+=__shfl_xor(s2,2);
    float mu=s*(1.f/128.f), var=fmaxf(s2*(1.f/128.f)-mu*mu,0.f);
    float rr=rsqrtf(var+1e-5f);
    for(int c=qq*32;c<qq*32+32;c+=2){
      float v0=(mf[row*132+c  ]-mu)*rr*bf2f(cb[4736+c  ])+bf2f(cb[4864+c  ]);
      float v1=(mf[row*132+c+1]-mu)*rr*bf2f(cb[4736+c+1])+bf2f(cb[4864+c+1]);
      *(unsigned int*)(h+(size_t)(m0+row)*128+c)=pack2(v0,v1);
    }
  }
}

// ---------------- UV generation: U = h@W1a + b1, V = h@W1b ----------------
__global__ __launch_bounds__(256) void uvgen_kernel(
  const unsigned short* __restrict__ hrows, const unsigned short* __restrict__ w1t,
  const unsigned short* __restrict__ b1, unsigned short* __restrict__ UV)
{
  __shared__ __align__(16) unsigned short a_t[64][136];
  int t=threadIdx.x;
  int m0=blockIdx.x*64;
  int y=blockIdx.y;
  for(int c=t;c<1024;c+=256){
    int m=c>>4, pp=c&15;
    *(uint4*)&a_t[m][pp*8]=*((const uint4*)(hrows+(size_t)(m0+m)*128)+pp);
  }
  __syncthreads();
  int lane=t&63, w=t>>6, quad=lane>>4, ln=lane&15;
  #pragma unroll
  for(int nt=0;nt<2;nt++){
    int n=w*32+nt*16+ln;
    f32x4 a0={0,0,0,0},a1={0,0,0,0},a2={0,0,0,0},a3={0,0,0,0};
    const unsigned short* wp=w1t+(size_t)n*256+y*128+quad*8;
    #pragma unroll
    for(int k0=0;k0<128;k0+=32){
      bf16x8 bfr=*(const bf16x8*)(wp+k0);
      bf16x8 f0=*(const bf16x8*)(&a_t[ln   ][k0+quad*8]);
      bf16x8 f1=*(const bf16x8*)(&a_t[16+ln][k0+quad*8]);
      bf16x8 f2=*(const bf16x8*)(&a_t[32+ln][k0+quad*8]);
      bf16x8 f3=*(const bf16x8*)(&a_t[48+ln][k0+quad*8]);
      a0=__builtin_amdgcn_mfma_f32_16x16x32_bf16(f0,bfr,a0,0,0,0);
      a1=__builtin_amdgcn_mfma_f32_16x16x32_bf16(f1,bfr,a1,0,0,0);
      a2=__builtin_amdgcn_mfma_f32_16x16x32_bf16(f2,bfr,a2,0,0,0);
      a3=__builtin_amdgcn_mfma_f32_16x16x32_bf16(f3,bfr,a3,0,0,0);
    }
    float bv=y?0.f:bf2f(b1[n]);
    #pragma unroll
    for(int r2=0;r2<4;r2++){
      UV[(size_t)(m0+quad*4+r2   )*256+y*128+n]=f2bf(a0[r2]+bv);
      UV[(size_t)(m0+16+quad*4+r2)*256+y*128+n]=f2bf(a1[r2]+bv);
      UV[(size_t)(m0+32+quad*4+r2)*256+y*128+n]=f2bf(a2[r2]+bv);
      UV[(size_t)(m0+48+quad*4+r2)*256+y*128+n]=f2bf(a3[r2]+bv);
    }
  }
}

// ---------------- fused edge phase: branchless gather (fast gelu) + k-split GEMV; XCD-local swizzle ----------------
__global__ __launch_bounds__(128) void edgef_kernel(
  unsigned short* __restrict__ h,
  const unsigned short* __restrict__ UV,      // local rows [gEp*512][256]
  const unsigned short* __restrict__ ss,
  const int* __restrict__ rowptr,
  const unsigned short* __restrict__ w2k,     // [128k][128n]
  const unsigned short* __restrict__ b2,
  const unsigned short* __restrict__ gg, const unsigned short* __restrict__ bbp,
  int b0, int gEp)
{
  __shared__ __align__(16) float aggL[2][4][128];
  __shared__ __align__(16) float po[2][4][128];
  int t=threadIdx.x, lane=t&63, w=t>>6;
  int bid=blockIdx.x;
  int lg=bid%gEp, ch=bid/gEp;     // ch in [0,128): 4-dst chunk
  int g=b0+lg;
  const unsigned short* UVg = UV + (size_t)lg*512*256;
  const unsigned short* ssg = ss + (size_t)g*E_;
  int dbase = ch*4;
  int bnd[5];
  #pragma unroll
  for(int i=0;i<5;i++) bnd[i]=rowptr[g*513+dbase+i];
  // ---- gather: wave w takes its half of each dst's edge range (branchless, masked idx) ----
  #pragma unroll 1
  for(int dd=0;dd<4;dd++){
    int e_lo=bnd[dd], e_hi0=bnd[dd+1];
    int half=(e_hi0-e_lo+1)>>1;
    int es = w ? (e_lo+half) : e_lo;
    int ee = w ? e_hi0       : (e_lo+half);
    unsigned int vdw=*(const unsigned int*)(UVg + (size_t)(dbase+dd)*256 + 128 + lane*2);
    float v0=bf2f((unsigned short)(vdw&0xffffu)), v1=bf2f((unsigned short)(vdw>>16));
    float a0=0.f, a1=0.f;
    int si3,si4,si5;
    unsigned int u0,u1,u2;
    {
      // over-reads (<=6 u16 past range) stay in-ws; idx masked &511
      int s0=__builtin_amdgcn_readfirstlane((int)ssg[es  ])&511;
      int s1=__builtin_amdgcn_readfirstlane((int)ssg[es+1])&511;
      int s2=__builtin_amdgcn_readfirstlane((int)ssg[es+2])&511;
      si3=(int)ssg[es+3]; si4=(int)ssg[es+4]; si5=(int)ssg[es+5];
      u0=*(const unsigned int*)(UVg + (size_t)s0*256 + lane*2);
      u1=*(const unsigned int*)(UVg + (size_t)s1*256 + lane*2);
      u2=*(const unsigned int*)(UVg + (size_t)s2*256 + lane*2);
    }
    #pragma unroll 2
    for(int e=es;e<ee;e++){
      float z0=bf2f((unsigned short)(u0&0xffffu))+v0;
      float z1=bf2f((unsigned short)(u0>>16))+v1;
      u0=u1; u1=u2;
      int s3=__builtin_amdgcn_readfirstlane(si3)&511;
      u2=*(const unsigned int*)(UVg + (size_t)s3*256 + lane*2);
      si3=si4; si4=si5;
      si5=(int)ssg[e+6];
      a0+=gelu_t(z0); a1+=gelu_t(z1);
    }
    aggL[w][dd][lane*2  ]=a0;
    aggL[w][dd][lane*2+1]=a1;
  }
  __syncthreads();
  // ---- GEMV k-split: wave w does all 4 dst over k in [w*64, w*64+64) ----
  float o[4][2];
  #pragma unroll
  for(int dd=0;dd<4;dd++){ o[dd][0]=0.f; o[dd][1]=0.f; }
  #pragma unroll 4
  for(int kk=0;kk<64;kk++){
    int k=w*64+kk;
    unsigned int wdw=*(const unsigned int*)(w2k+(size_t)k*128+lane*2);
    float w0=bf2f((unsigned short)(wdw&0xffffu));
    float w1=bf2f((unsigned short)(wdw>>16));
    #pragma unroll
    for(int dd=0;dd<4;dd++){
      float av=aggL[0][dd][k]+aggL[1][dd][k];
      o[dd][0]+=av*w0; o[dd][1]+=av*w1;
    }
  }
  #pragma unroll
  for(int dd=0;dd<4;dd++){
    po[w][dd][lane*2  ]=o[dd][0];
    po[w][dd][lane*2+1]=o[dd][1];
  }
  __syncthreads();
  // ---- combine partials + deg*b2 + residual + LN: wave w owns dst pair {2w, 2w+1} ----
  #pragma unroll 1
  for(int p=0;p<2;p++){
    int di=w*2+p;
    int d = dbase + di;
    float deg=(float)(bnd[di+1]-bnd[di]);
    float o0=bf2f(b2[lane*2  ])*deg + po[0][di][lane*2  ] + po[1][di][lane*2  ];
    float o1=bf2f(b2[lane*2+1])*deg + po[0][di][lane*2+1] + po[1][di][lane*2+1];
    size_t base=(size_t)(g*512+d)*128;
    unsigned int hdw=*(const unsigned int*)(h+base+lane*2);
    float x0=bf2f((unsigned short)(hdw&0xffffu))+o0;
    float x1=bf2f((unsigned short)(hdw>>16))+o1;
    float s1=x0+x1, s2=x0*x0+x1*x1;
    #pragma unroll
    for(int off=32;off>0;off>>=1){ s1+=__shfl_xor(s1,off); s2+=__shfl_xor(s2,off); }
    float mu=s1*(1.f/128.f), var=fmaxf(s2*(1.f/128.f)-mu*mu,0.f);
    float rr=rsqrtf(var+1e-5f);
    float y0=(x0-mu)*rr*bf2f(gg[lane*2  ])+bf2f(bbp[lane*2  ]);
    float y1=(x1-mu)*rr*bf2f(gg[lane*2+1])+bf2f(bbp[lane*2+1]);
    *(unsigned int*)(h+base+lane*2)=pack2(y0,y1);
  }
}

// ---------------- fused QKV + flash attention: per (graph, head, q-QUARTER), XCD-local swizzle ----------------
__global__ __launch_bounds__(256) void attnf_kernel(
  const unsigned short* __restrict__ h, const unsigned short* __restrict__ wqkv,
  const unsigned short* __restrict__ bq, unsigned short* __restrict__ obuf, int b0, int gA)
{
  __shared__ __align__(16) unsigned short Qs[128][40];
  __shared__ __align__(16) unsigned short Ks[64][72];
  __shared__ __align__(16) unsigned short Vts[32][72];
  __shared__ __align__(16) unsigned short Ps[64][72];
  int bx=blockIdx.x;
  int lg=bx%gA; int rr2=bx/gA; int hh=rr2&3, qq4=rr2>>2;
  int g=b0+lg;
  int t=threadIdx.x, lane=t&63, w=t>>6, quad=lane>>4, ln=lane&15;
  const unsigned short* hg=h+(size_t)g*512*128;
  const float sc=0.17677669529663689f;
  bf16x8 wk[2][4], wv[2][4];
  #pragma unroll
  for(int nt=0;nt<2;nt++)
    #pragma unroll
    for(int k0i=0;k0i<4;k0i++){
      int n=hh*32+nt*16+ln;
      wk[nt][k0i]=*(const bf16x8*)(wqkv+(size_t)(128+n)*128+k0i*32+quad*8);
      wv[nt][k0i]=*(const bf16x8*)(wqkv+(size_t)(256+n)*128+k0i*32+quad*8);
    }
  #pragma unroll
  for(int qt=0;qt<2;qt++){
    int r0=qq4*128+qt*64+w*16;
    bf16x8 af[4];
    #pragma unroll
    for(int k0i=0;k0i<4;k0i++) af[k0i]=*(const bf16x8*)(hg+(size_t)(r0+ln)*128+k0i*32+quad*8);
    #pragma unroll
    for(int nt=0;nt<2;nt++){
      int dim=nt*16+ln;
      f32x4 c={0,0,0,0};
      #pragma unroll
      for(int k0i=0;k0i<4;k0i++){
        bf16x8 bfr=*(const bf16x8*)(wqkv+(size_t)(hh*32+dim)*128+k0i*32+quad*8);
        c=__builtin_amdgcn_mfma_f32_16x16x32_bf16(af[k0i],bfr,c,0,0,0);
      }
      float bv=bf2f(bq[hh*32+dim]);
      #pragma unroll
      for(int r=0;r<4;r++) Qs[qt*64+w*16+quad*4+r][dim]=f2bf((c[r]+bv)*sc);
    }
  }
  f32x4 O[2][2]; float Lp[2][4];
  #pragma unroll
  for(int qt=0;qt<2;qt++){ O[qt][0]={0,0,0,0}; O[qt][1]={0,0,0,0};
    #pragma unroll
    for(int r=0;r<4;r++) Lp[qt][r]=0.f; }
  for(int kc=0;kc<8;kc++){
    __syncthreads();
    {
      int r0=kc*64+w*16;
      bf16x8 af[4];
      #pragma unroll
      for(int k0i=0;k0i<4;k0i++) af[k0i]=*(const bf16x8*)(hg+(size_t)(r0+ln)*128+k0i*32+quad*8);
      #pragma unroll
      for(int nt=0;nt<2;nt++){
        int dim=nt*16+ln;
        f32x4 ck={0,0,0,0}, cv={0,0,0,0};
        #pragma unroll
        for(int k0i=0;k0i<4;k0i++){
          ck=__builtin_amdgcn_mfma_f32_16x16x32_bf16(af[k0i],wk[nt][k0i],ck,0,0,0);
          cv=__builtin_amdgcn_mfma_f32_16x16x32_bf16(af[k0i],wv[nt][k0i],cv,0,0,0);
        }
        float bk=bf2f(bq[128+hh*32+dim]), bv2=bf2f(bq[256+hh*32+dim]);
        #pragma unroll
        for(int r=0;r<4;r++){
          int key=w*16+quad*4+r;
          Ks[key][dim]=f2bf(ck[r]+bk);
          Vts[dim][key]=f2bf(cv[r]+bv2);
        }
      }
    }
    __syncthreads();
    #pragma unroll
    for(int qt=0;qt<2;qt++){
      bf16x8 qf=*(const bf16x8*)(&Qs[qt*64+w*16+ln][quad*8]);
      f32x4 s[4];
      #pragma unroll
      for(int f=0;f<4;f++){
        bf16x8 kf=*(const bf16x8*)(&Ks[f*16+ln][quad*8]);
        f32x4 z={0,0,0,0};
        s[f]=__builtin_amdgcn_mfma_f32_16x16x32_bf16(qf,kf,z,0,0,0);
      }
      #pragma unroll
      for(int f=0;f<4;f++)
        #pragma unroll
        for(int r=0;r<4;r++){
          float pe=__expf(fminf(s[f][r],30.0f));
          Ps[w*16+quad*4+r][f*16+ln]=f2bf(pe);
          Lp[qt][r]+=pe;
        }
      #pragma unroll
      for(int s2=0;s2<2;s2++){
        bf16x8 pf=*(const bf16x8*)(&Ps[w*16+ln][s2*32+quad*8]);
        bf16x8 v0=*(const bf16x8*)(&Vts[ln   ][s2*32+quad*8]);
        bf16x8 v1=*(const bf16x8*)(&Vts[16+ln][s2*32+quad*8]);
        O[qt][0]=__builtin_amdgcn_mfma_f32_16x16x32_bf16(pf,v0,O[qt][0],0,0,0);
        O[qt][1]=__builtin_amdgcn_mfma_f32_16x16x32_bf16(pf,v1,O[qt][1],0,0,0);
      }
    }
  }
  #pragma unroll
  for(int qt=0;qt<2;qt++){
    #pragma unroll
    for(int o=1;o<16;o<<=1)
      #pragma unroll
      for(int r=0;r<4;r++) Lp[qt][r]+=__shfl_xor(Lp[qt][r],o);
    #pragma unroll
    for(int r=0;r<4;r++){
      float inv=1.0f/Lp[qt][r];
      size_t row=(size_t)lg*512+qq4*128+qt*64+w*16+quad*4+r;
      obuf[row*128+hh*32+ln   ]=f2bf(O[qt][0][r]*inv);
      obuf[row*128+hh*32+16+ln]=f2bf(O[qt][1][r]*inv);
    }
  }
}

// ---------------- oproj + residual + LN ----------------
__global__ __launch_bounds__(256) void oproj_kernel(
  const unsigned short* __restrict__ obuf, const unsigned short* __restrict__ wo,
  const unsigned short* __restrict__ bo, unsigned short* __restrict__ h,
  const unsigned short* __restrict__ gg, const unsigned short* __restrict__ bbp, int b0)
{
  __shared__ __align__(16) unsigned short a_t[64][136];
  __shared__ float mf[64][132];
  int t=threadIdx.x, lane=t&63, w=t>>6, quad=lane>>4, ln=lane&15;
  int m0=blockIdx.x*64;
  for(int c=t;c<64*16;c+=256){
    int m=c>>4, pp=c&15;
    *(uint4*)&a_t[m][pp*8]=*((const uint4*)(obuf+(size_t)(m0+m)*128)+pp);
  }
  __syncthreads();
  #pragma unroll
  for(int nt=0;nt<2;nt++){
    int n=w*32+nt*16+ln;
    f32x4 a0={0,0,0,0},a1={0,0,0,0},a2={0,0,0,0},a3={0,0,0,0};
    const unsigned short* wp=wo+(size_t)n*128+quad*8;
    #pragma unroll
    for(int k0=0;k0<128;k0+=32){
      bf16x8 bfr=*(const bf16x8*)(wp+k0);
      bf16x8 f0=*(const bf16x8*)(&a_t[ln   ][k0+quad*8]);
      bf16x8 f1=*(const bf16x8*)(&a_t[16+ln][k0+quad*8]);
      bf16x8 f2=*(const bf16x8*)(&a_t[32+ln][k0+quad*8]);
      bf16x8 f3=*(const bf16x8*)(&a_t[48+ln][k0+quad*8]);
      a0=__builtin_amdgcn_mfma_f32_16x16x32_bf16(f0,bfr,a0,0,0,0);
      a1=__builtin_amdgcn_mfma_f32_16x16x32_bf16(f1,bfr,a1,0,0,0);
      a2=__builtin_amdgcn_mfma_f32_16x16x32_bf16(f2,bfr,a2,0,0,0);
      a3=__builtin_amdgcn_mfma_f32_16x16x32_bf16(f3,bfr,a3,0,0,0);
    }
    float bv=bf2f(bo[n]);
    #pragma unroll
    for(int r=0;r<4;r++){
      mf[quad*4+r   ][n]=a0[r]+bv;
      mf[16+quad*4+r][n]=a1[r]+bv;
      mf[32+quad*4+r][n]=a2[r]+bv;
      mf[48+quad*4+r][n]=a3[r]+bv;
    }
  }
  __syncthreads();
  {
    int row=t>>2, qq=t&3;
    size_t base=(size_t)(b0*512+m0+row)*128;
    float s=0.f,s2=0.f;
    float vals[32];
    for(int j=0;j<32;j++){
      int c=qq*32+j;
      float v=bf2f(h[base+c])+mf[row][c];
      vals[j]=v; s+=v; s2+=v*v;
    }
    s+=__shfl_xor(s,1); s+=__shfl_xor(s,2);
    s2+=__shfl_xor(s2,1); s2+=__shfl_xor(s2,2);
    float mu=s*(1.f/128.f), var=fmaxf(s2*(1.f/128.f)-mu*mu,0.f);
    float rr=rsqrtf(var+1e-5f);
    for(int j=0;j<32;j+=2){
      int c=qq*32+j;
      float v0=(vals[j]  -mu)*rr*bf2f(gg[c  ])+bf2f(bbp[c  ]);
      float v1=(vals[j+1]-mu)*rr*bf2f(gg[c+1])+bf2f(bbp[c+1]);
      *(unsigned int*)(h+base+c)=pack2(v0,v1);
    }
  }
}

// ---------------- pooling partials ----------------
__global__ __launch_bounds__(256) void poolp_kernel(
  const unsigned short* __restrict__ h, float* __restrict__ part)
{
  __shared__ float ps[256], ps2[256], pm[256];
  int b=blockIdx.x, c=blockIdx.y;
  int t=threadIdx.x, d=t&127, hf=t>>7;
  float s=0.f,s2=0.f,mx=-1e30f;
  for(int r=hf*32;r<hf*32+32;r++){
    float v=bf2f(h[((size_t)(b*512+c*64+r))*128+d]);
    s+=v; s2+=v*v; mx=fmaxf(mx,v);
  }
  ps[t]=s; ps2[t]=s2; pm[t]=mx;
  __syncthreads();
  if(t<128){
    s=ps[t]+ps[128+t]; s2=ps2[t]+ps2[128+t]; mx=fmaxf(pm[t],pm[128+t]);
    size_t base=((size_t)(b*8+c))*384;
    part[base+t]=s; part[base+128+t]=s2; part[base+256+t]=mx;
  }
}

// ---------------- graph head: finalize pooling + MLP ----------------
__global__ __launch_bounds__(256) void head_kernel(
  const float* __restrict__ part, const unsigned short* __restrict__ ghw1t,
  const unsigned short* __restrict__ ghw2t, const unsigned short* __restrict__ cb,
  void* __restrict__ out, const int* __restrict__ flag)
{
  int isbf=*flag;
  int b=blockIdx.x, t=threadIdx.x;
  __shared__ float pl[512];
  __shared__ float gl[256];
  __shared__ float red[16];
  if(t<128){
    float s=0.f,s2=0.f,mx=-1e30f;
    for(int c=0;c<8;c++){
      size_t base=((size_t)(b*8+c))*384;
      s += part[base+t];
      s2+= part[base+128+t];
      mx = fmaxf(mx, part[base+256+t]);
    }
    float mean=s*(1.f/512.f);
    float var=fmaxf(s2*(1.f/512.f)-mean*mean,0.f);
    float sd=sqrtf(var+1e-6f);
    pl[t]=mean; pl[128+t]=s; pl[256+t]=mx; pl[384+t]=sd;
  }
  __syncthreads();
  float a=bf2f(cb[4992+t]);
  const unsigned short* wr=ghw1t+(size_t)t*512;
  for(int k0=0;k0<512;k0+=8){
    bf16x8 wv=*(const bf16x8*)(wr+k0);
    const unsigned short* wp=(const unsigned short*)&wv;
    #pragma unroll
    for(int j=0;j<8;j++) a+=pl[k0+j]*bf2f(wp[j]);
  }
  float u=gelu_f(a);
  float S,S2; block_sum2(u,u*u,S,S2,red,4);
  float mu=S*(1.f/256.f), var=fmaxf(S2*(1.f/256.f)-mu*mu,0.f);
  float r=rsqrtf(var+1e-5f);
  gl[t]=(u-mu)*r*bf2f(cb[5248+t])+bf2f(cb[5504+t]);
  __syncthreads();
  if(t<10){
    float o=bf2f(cb[5760+t]);
    const unsigned short* wr2=ghw2t+(size_t)t*256;
    for(int k0=0;k0<256;k0+=8){
      bf16x8 wv=*(const bf16x8*)(wr2+k0);
      const unsigned short* wp=(const unsigned short*)&wv;
      #pragma unroll
      for(int j=0;j<8;j++) o+=gl[k0+j]*bf2f(wp[j]);
    }
    if(isbf) ((unsigned short*)out)[b*10+t]=f2bf(o);
    else     ((float*)out)[b*10+t]=o;
  }
}

extern "C" void kernel_launch(void* const* d_in, const int* in_sizes, int n_in,
                              void* d_out, int out_size, void* d_ws, size_t ws_size,
                              hipStream_t stream)
{
  const void* x      =d_in[0];
  const int*  src    =(const int*)d_in[1];
  const int*  dstp   =(const int*)d_in[2];
  const void* enc_w1 =d_in[3];  const void* enc_b1 =d_in[4];
  const void* enc_g1 =d_in[5];  const void* enc_bn1=d_in[6];
  const void* enc_w2 =d_in[7];  const void* enc_b2 =d_in[8];
  const void* enc_g2 =d_in[9];  const void* enc_bn2=d_in[10];
  const void* msg_w1 =d_in[11]; const void* msg_b1 =d_in[12];
  const void* msg_w2 =d_in[13]; const void* msg_b2 =d_in[14];
  const void* msg_g  =d_in[15]; const void* msg_bb =d_in[16];
  const void* qw     =d_in[17]; const void* qb     =d_in[18];
  const void* kw     =d_in[19]; const void* kb     =d_in[20];
  const void* vw     =d_in[21]; const void* vb     =d_in[22];
  const void* ow     =d_in[23]; const void* ob     =d_in[24];
  const void* attn_g =d_in[25]; const void* attn_b =d_in[26];
  const void* gh_w1  =d_in[27]; const void* gh_b1  =d_in[28];
  const void* gh_g   =d_in[29]; const void* gh_bn  =d_in[30];
  const void* gh_w2  =d_in[31]; const void* gh_b2  =d_in[32];
  (void)in_sizes; (void)n_in; (void)out_size;

  const size_t MB=1024*1024;
  char* base=(char*)d_ws;
  unsigned short* h    =(unsigned short*)(base);                 // 4 MB
  unsigned short* w1t  =(unsigned short*)(base + 4194304);
  unsigned short* w2k  =(unsigned short*)(base + 4390912);
  unsigned short* qkvt =(unsigned short*)(base + 4489216);
  unsigned short* owt  =(unsigned short*)(base + 4784128);
  unsigned short* w1te =(unsigned short*)(base + 4882432);
  unsigned short* w2te =(unsigned short*)(base + 4915200);
  unsigned short* ghw1t=(unsigned short*)(base + 4980736);
  unsigned short* ghw2t=(unsigned short*)(base + 5242880);
  unsigned short* cb   =(unsigned short*)(base + 5248000);
  int*   rowptr        =(int*)(base + 5325312);                  // 65664 B
  int*   flag          =(int*)(base + 5390976);
  int*   cnt           =(int*)(base + 5391360);                  // 65536 B sort counters
  unsigned short* ssrt =(unsigned short*)(base + 5505024);       // 512 KB (+edgef over-reads land in R)
  char* R              = base + 6029312;                          // shared region

  int epass, apass;
  if(ws_size >= (size_t)(14.5*MB)){ epass=1; apass=1; }
  else if(ws_size >= 10*MB){ epass=2; apass=1; }
  else { epass=4; apass=2; }
  int gEp=B_/epass, gA=B_/apass;
  int rowsA=gA*512;
  float* part=(float*)R;   // pool partials: 32*8*384*4 = 393 KB (R free after layer loop)

  sniff_kernel<<<1,64,0,stream>>>((const unsigned int*)x, flag);
  hipMemsetAsync(cnt,0,65536,stream);
  count_kernel<<<dim3(B_,8),256,0,stream>>>(dstp,cnt);
  scan_kernel<<<B_,256,0,stream>>>(cnt,rowptr);
  scatter_kernel<<<dim3(B_,8),256,0,stream>>>(src,dstp,cnt,ssrt);
  prep_kernel<<<dim3(128,27),256,0,stream>>>(msg_w1,msg_w2,qw,kw,vw,ow,qb,kb,vb,
      ob,msg_b1,msg_b2,msg_g,msg_bb,attn_g,attn_b,
      enc_w1,enc_w2,enc_b1,enc_g1,enc_bn1,enc_b2,enc_g2,enc_bn2,
      gh_w1,gh_w2,gh_b1,gh_g,gh_bn,gh_b2,
      w1t,w2k,qkvt,owt,w1te,w2te,ghw1t,ghw2t,cb,flag);

  enc_kernel<<<BN_/64,256,0,stream>>>(x,w1te,w2te,cb,h,flag);

  for(int l=0;l<3;l++){
    for(int ep=0;ep<epass;ep++){
      int b0=ep*gEp;
      unsigned short* UV=(unsigned short*)R;   // gEp*512 x 256 bf16
      uvgen_kernel<<<dim3(gEp*8,2),256,0,stream>>>(h+(size_t)b0*512*128,
          w1t+(size_t)l*32768, cb+1536+l*128, UV);
      edgef_kernel<<<gEp*128,128,0,stream>>>(h,UV,ssrt,rowptr,
          w2k+(size_t)l*16384, cb+1920+l*128, cb+2304+l*128, cb+2688+l*128, b0, gEp);
    }
    for(int ap=0;ap<apass;ap++){
      int b0=ap*gA;
      unsigned short* obuf=(unsigned short*)R;
      attnf_kernel<<<gA*16,256,0,stream>>>(h, qkvt+(size_t)l*49152, cb+l*384, obuf, b0, gA);
      oproj_kernel<<<rowsA/64,256,0,stream>>>(obuf, owt+(size_t)l*16384,
          cb+1152+l*128, h, cb+3072+l*128, cb+3456+l*128, b0);
    }
  }
  poolp_kernel<<<dim3(B_,8),256,0,stream>>>(h,part);
  head_kernel<<<B_,256,0,stream>>>(part,ghw1t,ghw2t,cb,d_out,flag);
}